// Round 14
// baseline (122.492 us; speedup 1.0000x reference)
//
#include <hip/hip_runtime.h>
#include <cfloat>
#include <cstdint>
#include <cstddef>

using u16 = unsigned short;
typedef __attribute__((ext_vector_type(8))) short short8;
typedef __attribute__((ext_vector_type(4))) float f32x4;

#define HEADS 6
#define NSEQ 4096
#define SCALEF 0.125f
#define LOG2E 1.4426950408889634f
#define SC2 (SCALEF * LOG2E)

#if __has_builtin(__builtin_amdgcn_exp2f)
#define EXP2(x) __builtin_amdgcn_exp2f(x)
#else
#define EXP2(x) exp2f(x)
#endif

__device__ __forceinline__ u16 f2bf_rn(float f) {
  unsigned int u = __builtin_bit_cast(unsigned int, f);
  u = (u + 0x7FFFu + ((u >> 16) & 1u)) >> 16;
  return (u16)u;
}

__device__ __forceinline__ void gload_lds16(const void* g, void* l) {
  __builtin_amdgcn_global_load_lds((const __attribute__((address_space(1))) void*)g,
                                   (__attribute__((address_space(3))) void*)l, 16, 0, 0);
}

// Swizzled b128 read from a [rows][64] u16 LDS tile (128B rows). (GEMM use)
__device__ __forceinline__ short8 frag_read(const u16* tile, int row, int blk) {
  int byt = row * 128 + ((blk * 16) ^ ((row & 7) << 4));
  return *(const short8*)((const char*)tile + byt);
}

__device__ __forceinline__ void cast8(const float* __restrict__ s, u16* __restrict__ d, int i) {
  const float4* sp = (const float4*)s;
  float4 a = sp[2 * i], b = sp[2 * i + 1];
  short8 r;
  r[0] = (short)f2bf_rn(a.x); r[1] = (short)f2bf_rn(a.y);
  r[2] = (short)f2bf_rn(a.z); r[3] = (short)f2bf_rn(a.w);
  r[4] = (short)f2bf_rn(b.x); r[5] = (short)f2bf_rn(b.y);
  r[6] = (short)f2bf_rn(b.z); r[7] = (short)f2bf_rn(b.w);
  ((short8*)d)[i] = r;
}

// fused prep: cast x / w_qkv / w_proj to bf16 + mask -> float addend
__global__ void prep_kernel(const float* __restrict__ x, const float* __restrict__ wqkv,
                            const float* __restrict__ wproj, const int* __restrict__ mask,
                            u16* __restrict__ xb, u16* __restrict__ wqb, u16* __restrict__ wpb,
                            float* __restrict__ madd) {
  const int NX = 3145728 / 8, NQ = 442368 / 8, NP = 147456 / 8;
  int i = blockIdx.x * blockDim.x + threadIdx.x;
  if (i < NX) cast8(x, xb, i);
  else if (i < NX + NQ) cast8(wqkv, wqb, i - NX);
  else if (i < NX + NQ + NP) cast8(wproj, wpb, i - NX - NQ);
  else {
    int j = i - (NX + NQ + NP);
    if (j < 2 * NSEQ) madd[j] = mask[j] ? 0.f : -FLT_MAX;
  }
}

// C = A(MxK) * B(NxK)^T ; 128x128 tile, BK=64, 4 waves (2x2 of 64x64).
template <int EPI>
__launch_bounds__(256)
__global__ void gemm_bt(const u16* __restrict__ A, const u16* __restrict__ B,
                        int Kdim, int Ndim,
                        u16* __restrict__ q_out, u16* __restrict__ k_out, u16* __restrict__ vt_out,
                        const float* __restrict__ bias, float* __restrict__ out) {
  __shared__ u16 lA[128 * 64];
  __shared__ u16 lB[128 * 64];
  int brow = blockIdx.x, bcol = blockIdx.y;
  int tid = threadIdx.x;
  int w = tid >> 6, lane = tid & 63;
  int wr = w >> 1, wc = w & 1;
  int r_in = lane >> 3;
  int jblk = (lane & 7) ^ r_in;
  int l15 = lane & 15, lg = lane >> 4;

  f32x4 acc[4][4];
#pragma unroll
  for (int i = 0; i < 4; i++)
#pragma unroll
    for (int j = 0; j < 4; j++) acc[i][j] = (f32x4){0.f, 0.f, 0.f, 0.f};

  const u16* Ab = A + (size_t)(brow * 128 + w * 32 + r_in) * Kdim + jblk * 8;
  const u16* Bb = B + (size_t)(bcol * 128 + w * 32 + r_in) * Kdim + jblk * 8;

  int ksteps = Kdim >> 6;
  for (int kt = 0; kt < ksteps; ++kt) {
    __syncthreads();
#pragma unroll
    for (int c = 0; c < 4; ++c) {
      gload_lds16(Ab + kt * 64 + (size_t)(c * 8) * Kdim, &lA[(w * 32 + c * 8) * 64]);
      gload_lds16(Bb + kt * 64 + (size_t)(c * 8) * Kdim, &lB[(w * 32 + c * 8) * 64]);
    }
    asm volatile("s_waitcnt vmcnt(0)" ::: "memory");
    __syncthreads();

    short8 af[4][2], bfr[4][2];
#pragma unroll
    for (int ms = 0; ms < 4; ++ms)
#pragma unroll
      for (int hf = 0; hf < 2; ++hf)
        af[ms][hf] = frag_read(lA, wr * 64 + ms * 16 + l15, hf * 4 + lg);
#pragma unroll
    for (int ns = 0; ns < 4; ++ns)
#pragma unroll
      for (int hf = 0; hf < 2; ++hf)
        bfr[ns][hf] = frag_read(lB, wc * 64 + ns * 16 + l15, hf * 4 + lg);
#pragma unroll
    for (int ms = 0; ms < 4; ++ms)
#pragma unroll
      for (int ns = 0; ns < 4; ++ns) {
        acc[ms][ns] = __builtin_amdgcn_mfma_f32_16x16x32_bf16(af[ms][0], bfr[ns][0], acc[ms][ns], 0, 0, 0);
        acc[ms][ns] = __builtin_amdgcn_mfma_f32_16x16x32_bf16(af[ms][1], bfr[ns][1], acc[ms][ns], 0, 0, 0);
      }
  }

#pragma unroll
  for (int ms = 0; ms < 4; ++ms)
#pragma unroll
    for (int ns = 0; ns < 4; ++ns)
#pragma unroll
      for (int r = 0; r < 4; ++r) {
        int row_g = brow * 128 + wr * 64 + ms * 16 + lg * 4 + r;
        int col_g = bcol * 128 + wc * 64 + ns * 16 + l15;
        float v = acc[ms][ns][r];
        if (EPI == 0) {
          int t = col_g / 384;
          int rem = col_g - t * 384;
          int h = rem >> 6, d = rem & 63;
          int b = row_g >> 12, n = row_g & 4095;
          u16 val = f2bf_rn(v);
          size_t bh = (size_t)(b * HEADS + h);
          if (t == 0)      q_out[(bh * NSEQ + n) * 64 + d] = val;
          else if (t == 1) k_out[(bh * NSEQ + n) * 64 + d] = val;
          else             vt_out[(bh * 64 + d) * NSEQ + n] = val;
        } else {
          out[(size_t)row_g * Ndim + col_g] = v + bias[col_g];
        }
      }
}

// Flash attention, QBLK=32/wave, KT=64, streaming softmax, KS-way grid k-split
// writing f32 partials (R13-proven core; KS only changes kbase/NT/swizzle).
template <int KS>
__launch_bounds__(256, 3)
__global__ void attn_kernel32(const u16* __restrict__ qg, const u16* __restrict__ kg,
                              const u16* __restrict__ vtg, const float* __restrict__ madd,
                              float* __restrict__ o_part, float* __restrict__ l_part) {
  __shared__ u16 lK[64 * 64];   // [k_local][d], 128B rows, XOR key = row&7
  __shared__ u16 lV[64 * 64];   // [d][k_local], 128B rows, XOR key = row&7

  // bijective XCD swizzle: 32*12*KS blocks, 48*KS per XCD; qb fastest
  int bid = blockIdx.x;
  int orig = (bid & 7) * (48 * KS) + (bid >> 3);
  int qb = orig & 31;
  int rr = orig >> 5;              // 0 .. 12*KS-1
  int bh = rr % 12, kh = rr / 12;
  int kbase = kh * (NSEQ / KS);
  const int NT = (NSEQ / KS) / 64;

  int b = bh / HEADS;
  int tid = threadIdx.x;
  int w = tid >> 6, lane = tid & 63;
  int l15 = lane & 15, lg = lane >> 4;
  int r_in = lane >> 3, jblk = (lane & 7) ^ r_in;

  const u16* Q = qg + (size_t)bh * NSEQ * 64;
  const u16* K = kg + (size_t)bh * NSEQ * 64;
  const u16* VT = vtg + (size_t)bh * 64 * NSEQ;
  const float* marow = madd + b * NSEQ;

  int q0 = qb * 128 + w * 32;
  int qrow0 = q0 + l15, qrow1 = q0 + 16 + l15;
  short8 qfA[2], qfB[2];
#pragma unroll
  for (int hf = 0; hf < 2; ++hf) {
    qfA[hf] = *(const short8*)(Q + (size_t)qrow0 * 64 + hf * 32 + lg * 8);
    qfB[hf] = *(const short8*)(Q + (size_t)qrow1 * 64 + hf * 32 + lg * 8);
  }

  float qsel0 = (marow[qrow0] == 0.0f) ? 1.0f : 0.0f;
  float qsel1 = (marow[qrow1] == 0.0f) ? 1.0f : 0.0f;
  float scq0 = SC2 * qsel0, scq1 = SC2 * qsel1;

  // lane-constant swizzled read offsets (row = x*16 + l15 -> row&7 == l15&7)
  int swk = (l15 & 7) << 4;
  int offKA = l15 * 128 + ((lg * 16) ^ swk);
  int offKB = l15 * 128 + (((4 + lg) * 16) ^ swk);

  f32x4 acc0[4], acc1[4];
#pragma unroll
  for (int ds_ = 0; ds_ < 4; ++ds_) {
    acc0[ds_] = (f32x4){0.f, 0.f, 0.f, 0.f};
    acc1[ds_] = (f32x4){0.f, 0.f, 0.f, 0.f};
  }
  f32x4 lsum0 = (f32x4){0.f, 0.f, 0.f, 0.f};
  f32x4 lsum1 = (f32x4){0.f, 0.f, 0.f, 0.f};

  // STAGE (R2/R3-proven, 4 waves, KT=64): linear dest + pre-swizzled source
#define STAGE(k0s)                                                                      \
  {                                                                                     \
    _Pragma("unroll")                                                                   \
    for (int c = 0; c < 2; ++c) {                                                       \
      int rowb = w * 16 + c * 8;                                                        \
      gload_lds16(K + (size_t)((k0s) + rowb + r_in) * 64 + jblk * 8, &lK[rowb * 64]);   \
      gload_lds16(VT + (size_t)(rowb + r_in) * NSEQ + (k0s) + jblk * 8, &lV[rowb * 64]);\
    }                                                                                   \
  }

  STAGE(kbase);
  asm volatile("s_waitcnt vmcnt(0)" ::: "memory");
  __syncthreads();

  for (int t = 0; t < NT; ++t) {
    int k0 = kbase + t * 64;

    // S^T = K Q^T, both q-subtiles; kf read ONCE per cs
    f32x4 p0[4], p1[4];
    __builtin_amdgcn_s_setprio(1);
#pragma unroll
    for (int cs = 0; cs < 4; ++cs) {
      short8 kf0 = *(const short8*)((const char*)lK + offKA + cs * 2048);
      short8 kf1 = *(const short8*)((const char*)lK + offKB + cs * 2048);
      f32x4 z0 = (f32x4){0.f, 0.f, 0.f, 0.f};
      f32x4 z1 = (f32x4){0.f, 0.f, 0.f, 0.f};
      z0 = __builtin_amdgcn_mfma_f32_16x16x32_bf16(kf0, qfA[0], z0, 0, 0, 0);
      z1 = __builtin_amdgcn_mfma_f32_16x16x32_bf16(kf0, qfB[0], z1, 0, 0, 0);
      p0[cs] = __builtin_amdgcn_mfma_f32_16x16x32_bf16(kf1, qfA[1], z0, 0, 0, 0);
      p1[cs] = __builtin_amdgcn_mfma_f32_16x16x32_bf16(kf1, qfB[1], z1, 0, 0, 0);
    }
    __builtin_amdgcn_s_setprio(0);

    // streaming softmax; mask vector loaded once per cs
#pragma unroll
    for (int cs = 0; cs < 4; ++cs) {
      f32x4 mf = *(const f32x4*)(marow + k0 + cs * 16 + lg * 4);
      f32x4 d0 = p0[cs] * scq0 + mf * qsel0;
      f32x4 d1 = p1[cs] * scq1 + mf * qsel1;
#pragma unroll
      for (int r = 0; r < 4; ++r) {
        p0[cs][r] = EXP2(d0[r]);
        p1[cs][r] = EXP2(d1[r]);
      }
    }
    lsum0 += (p0[0] + p0[1]) + (p0[2] + p0[3]);
    lsum1 += (p1[0] + p1[1]) + (p1[2] + p1[3]);

    // dance: subtile A then B (keeps transient wd-state small)
    short8 pfA[2], pfB[2];
    {
      uint32_t wd[4][2];
#pragma unroll
      for (int cs = 0; cs < 4; ++cs)
#pragma unroll
        for (int hh = 0; hh < 2; ++hh)
          asm("v_cvt_pk_bf16_f32 %0, %1, %2" : "=v"(wd[cs][hh]) : "v"(p0[cs][2 * hh]), "v"(p0[cs][2 * hh + 1]));
#pragma unroll
      for (int c = 0; c < 2; ++c) {
        union { uint32_t u[4]; short8 s8; } cv;
#pragma unroll
        for (int hh = 0; hh < 2; ++hh) {
          uint32_t A = wd[2 * c][hh], B = wd[2 * c + 1][hh];
          asm("v_permlane32_swap_b32 %0, %1" : "+v"(A), "+v"(B));
          asm("v_permlane16_swap_b32 %0, %1" : "+v"(A), "+v"(B));
          cv.u[hh] = A;
          cv.u[2 + hh] = B;
        }
        pfA[c] = cv.s8;
      }
    }
    {
      uint32_t wd[4][2];
#pragma unroll
      for (int cs = 0; cs < 4; ++cs)
#pragma unroll
        for (int hh = 0; hh < 2; ++hh)
          asm("v_cvt_pk_bf16_f32 %0, %1, %2" : "=v"(wd[cs][hh]) : "v"(p1[cs][2 * hh]), "v"(p1[cs][2 * hh + 1]));
#pragma unroll
      for (int c = 0; c < 2; ++c) {
        union { uint32_t u[4]; short8 s8; } cv;
#pragma unroll
        for (int hh = 0; hh < 2; ++hh) {
          uint32_t A = wd[2 * c][hh], B = wd[2 * c + 1][hh];
          asm("v_permlane32_swap_b32 %0, %1" : "+v"(A), "+v"(B));
          asm("v_permlane16_swap_b32 %0, %1" : "+v"(A), "+v"(B));
          cv.u[hh] = A;
          cv.u[2 + hh] = B;
        }
        pfB[c] = cv.s8;
      }
    }

    // O^T += V^T P^T ; vf read ONCE per ds
    __builtin_amdgcn_s_setprio(1);
#pragma unroll
    for (int ds_ = 0; ds_ < 4; ++ds_) {
      short8 vf0 = *(const short8*)((const char*)lV + offKA + ds_ * 2048);
      short8 vf1 = *(const short8*)((const char*)lV + offKB + ds_ * 2048);
      acc0[ds_] = __builtin_amdgcn_mfma_f32_16x16x32_bf16(vf0, pfA[0], acc0[ds_], 0, 0, 0);
      acc0[ds_] = __builtin_amdgcn_mfma_f32_16x16x32_bf16(vf1, pfA[1], acc0[ds_], 0, 0, 0);
      acc1[ds_] = __builtin_amdgcn_mfma_f32_16x16x32_bf16(vf0, pfB[0], acc1[ds_], 0, 0, 0);
      acc1[ds_] = __builtin_amdgcn_mfma_f32_16x16x32_bf16(vf1, pfB[1], acc1[ds_], 0, 0, 0);
    }
    __builtin_amdgcn_s_setprio(0);

    __syncthreads();
    if (t + 1 < NT) {
      STAGE(k0 + 64);
      asm volatile("s_waitcnt vmcnt(0)" ::: "memory");
      __syncthreads();
    }
  }

  float rsum0 = (lsum0[0] + lsum0[1]) + (lsum0[2] + lsum0[3]);
  rsum0 += __shfl_xor(rsum0, 16);
  rsum0 += __shfl_xor(rsum0, 32);
  float rsum1 = (lsum1[0] + lsum1[1]) + (lsum1[2] + lsum1[3]);
  rsum1 += __shfl_xor(rsum1, 16);
  rsum1 += __shfl_xor(rsum1, 32);

  float* op = o_part + (size_t)kh * (8192ull * 384);
  int hd = bh - b * HEADS;
  size_t base0 = ((size_t)b * NSEQ + qrow0) * 384 + hd * 64;
  size_t base1 = ((size_t)b * NSEQ + qrow1) * 384 + hd * 64;
#pragma unroll
  for (int ds_ = 0; ds_ < 4; ++ds_) {
    *(f32x4*)(op + base0 + ds_ * 16 + lg * 4) = acc0[ds_];
    *(f32x4*)(op + base1 + ds_ * 16 + lg * 4) = acc1[ds_];
  }
  if (lg == 0) {
    l_part[(kh * 12 + bh) * NSEQ + qrow0] = rsum0;
    l_part[(kh * 12 + bh) * NSEQ + qrow1] = rsum1;
  }
#undef STAGE
}

// Fallback (R10-proven): QBLK=16, KT=128, no split, bf16 out directly.
__launch_bounds__(256, 3)
__global__ void attn_kernel16(const u16* __restrict__ qg, const u16* __restrict__ kg,
                              const u16* __restrict__ vtg, const float* __restrict__ madd,
                              u16* __restrict__ attn_out) {
  __shared__ u16 lK[128 * 64];
  __shared__ u16 lV[64 * 128];
  int bid = blockIdx.y * 64 + blockIdx.x;
  int orig = (bid & 7) * 96 + (bid >> 3);
  int qb = orig & 63, bh = orig >> 6;
  int b = bh / HEADS, hd = bh - b * HEADS;
  int q0 = qb * 64;
  int tid = threadIdx.x;
  int w = tid >> 6, lane = tid & 63;
  int l15 = lane & 15, lg = lane >> 4;
  int r_in = lane >> 3, jblk = (lane & 7) ^ r_in;
  const u16* Q = qg + (size_t)bh * NSEQ * 64;
  const u16* K = kg + (size_t)bh * NSEQ * 64;
  const u16* VT = vtg + (size_t)bh * 64 * NSEQ;
  const float* marow = madd + b * NSEQ;
  int qrow = q0 + w * 16 + l15;
  short8 qf[2];
#pragma unroll
  for (int hf = 0; hf < 2; ++hf)
    qf[hf] = *(const short8*)(Q + (size_t)qrow * 64 + hf * 32 + lg * 8);
  float qsel = (marow[qrow] == 0.0f) ? 1.0f : 0.0f;
  float scq = SC2 * qsel;
  int swk = (l15 & 7) << 4;
  int offKA = l15 * 128 + ((lg * 16) ^ swk);
  int offKB = l15 * 128 + (((4 + lg) * 16) ^ swk);
  int voff[4];
#pragma unroll
  for (int c = 0; c < 4; ++c) voff[c] = l15 * 256 + ((((c * 4 + lg) ^ l15)) << 4);
  f32x4 acc[4];
#pragma unroll
  for (int ds_ = 0; ds_ < 4; ++ds_) acc[ds_] = (f32x4){0.f, 0.f, 0.f, 0.f};
  f32x4 lsum = (f32x4){0.f, 0.f, 0.f, 0.f};
#define STAGE(k0s)                                                                    \
  {                                                                                   \
    _Pragma("unroll")                                                                 \
    for (int c = 0; c < 4; ++c) {                                                     \
      int krb = w * 32 + c * 8;                                                       \
      gload_lds16(K + (size_t)((k0s) + krb + r_in) * 64 + jblk * 8, &lK[krb * 64]);   \
      int vrb = w * 16 + c * 4;                                                       \
      int vsb = l15 ^ (c * 4 + lg);                                                   \
      gload_lds16(VT + (size_t)(vrb + lg) * NSEQ + (k0s) + vsb * 8, &lV[vrb * 128]);  \
    }                                                                                 \
  }
  STAGE(0);
  asm volatile("s_waitcnt vmcnt(0)" ::: "memory");
  __syncthreads();
  const int NT = NSEQ / 128;
  for (int t = 0; t < NT; ++t) {
    int k0 = t * 128;
    f32x4 p[8];
    __builtin_amdgcn_s_setprio(1);
#pragma unroll
    for (int cs = 0; cs < 8; ++cs) {
      short8 kf0 = *(const short8*)((const char*)lK + offKA + cs * 2048);
      short8 kf1 = *(const short8*)((const char*)lK + offKB + cs * 2048);
      f32x4 z = (f32x4){0.f, 0.f, 0.f, 0.f};
      z = __builtin_amdgcn_mfma_f32_16x16x32_bf16(kf0, qf[0], z, 0, 0, 0);
      p[cs] = __builtin_amdgcn_mfma_f32_16x16x32_bf16(kf1, qf[1], z, 0, 0, 0);
    }
    __builtin_amdgcn_s_setprio(0);
#pragma unroll
    for (int cs = 0; cs < 8; ++cs) {
      f32x4 mf = *(const f32x4*)(marow + k0 + cs * 16 + lg * 4);
      f32x4 d = p[cs] * scq + mf * qsel;
#pragma unroll
      for (int r = 0; r < 4; ++r) p[cs][r] = EXP2(d[r]);
    }
    lsum += ((p[0] + p[1]) + (p[2] + p[3])) + ((p[4] + p[5]) + (p[6] + p[7]));
    uint32_t wd[8][2];
#pragma unroll
    for (int cs = 0; cs < 8; ++cs)
#pragma unroll
      for (int hh = 0; hh < 2; ++hh)
        asm("v_cvt_pk_bf16_f32 %0, %1, %2" : "=v"(wd[cs][hh]) : "v"(p[cs][2 * hh]), "v"(p[cs][2 * hh + 1]));
    short8 pf[4];
#pragma unroll
    for (int c = 0; c < 4; ++c) {
      union { uint32_t u[4]; short8 s8; } cv;
#pragma unroll
      for (int hh = 0; hh < 2; ++hh) {
        uint32_t A = wd[2 * c][hh], B = wd[2 * c + 1][hh];
        asm("v_permlane32_swap_b32 %0, %1" : "+v"(A), "+v"(B));
        asm("v_permlane16_swap_b32 %0, %1" : "+v"(A), "+v"(B));
        cv.u[hh] = A;
        cv.u[2 + hh] = B;
      }
      pf[c] = cv.s8;
    }
    __builtin_amdgcn_s_setprio(1);
#pragma unroll
    for (int ds_ = 0; ds_ < 4; ++ds_)
#pragma unroll
      for (int c = 0; c < 4; ++c) {
        short8 vf = *(const short8*)((const char*)lV + voff[c] + ds_ * 4096);
        acc[ds_] = __builtin_amdgcn_mfma_f32_16x16x32_bf16(vf, pf[c], acc[ds_], 0, 0, 0);
      }
    __builtin_amdgcn_s_setprio(0);
    __syncthreads();
    if (t + 1 < NT) {
      STAGE(k0 + 128);
      asm volatile("s_waitcnt vmcnt(0)" ::: "memory");
      __syncthreads();
    }
  }
  float rsum = (lsum[0] + lsum[1]) + (lsum[2] + lsum[3]);
  rsum += __shfl_xor(rsum, 16);
  rsum += __shfl_xor(rsum, 32);
  float inv = 1.0f / rsum;
  size_t base = ((size_t)b * NSEQ + qrow) * 384 + hd * 64;
#pragma unroll
  for (int ds_ = 0; ds_ < 4; ++ds_) {
    uint32_t w0, w1;
    float a0 = acc[ds_][0] * inv, a1 = acc[ds_][1] * inv;
    float a2 = acc[ds_][2] * inv, a3 = acc[ds_][3] * inv;
    asm("v_cvt_pk_bf16_f32 %0, %1, %2" : "=v"(w0) : "v"(a0), "v"(a1));
    asm("v_cvt_pk_bf16_f32 %0, %1, %2" : "=v"(w1) : "v"(a2), "v"(a3));
    uint2 st; st.x = w0; st.y = w1;
    *(uint2*)(attn_out + base + ds_ * 16 + lg * 4) = st;
  }
#undef STAGE
}

// combine KS k-split partials: out = (sum O_kh) / (sum l_kh), cast bf16
template <int KS>
__global__ void combine_kernel(const float* __restrict__ o_part, const float* __restrict__ l_part,
                               u16* __restrict__ out) {
  int i = blockIdx.x * blockDim.x + threadIdx.x;   // float4 index, 786432 total
  int elem = i * 4;
  int ng = elem / 384;
  int cc = elem - ng * 384;
  int h = cc >> 6;
  int b = ng >> 12, n = ng & 4095;
  int li = (b * HEADS + h) * NSEQ + n;

  float4 a = ((const float4*)o_part)[i];
  float lt = l_part[li];
#pragma unroll
  for (int kh = 1; kh < KS; ++kh) {
    float4 c = ((const float4*)(o_part + (size_t)kh * (8192ull * 384)))[i];
    a.x += c.x; a.y += c.y; a.z += c.z; a.w += c.w;
    lt += l_part[kh * 12 * NSEQ + li];
  }
  float inv = 1.0f / lt;
  float a0 = a.x * inv, a1 = a.y * inv, a2 = a.z * inv, a3 = a.w * inv;
  uint32_t w0, w1;
  asm("v_cvt_pk_bf16_f32 %0, %1, %2" : "=v"(w0) : "v"(a0), "v"(a1));
  asm("v_cvt_pk_bf16_f32 %0, %1, %2" : "=v"(w1) : "v"(a2), "v"(a3));
  uint2 st; st.x = w0; st.y = w1;
  *(uint2*)(out + elem) = st;
}

extern "C" void kernel_launch(void* const* d_in, const int* in_sizes, int n_in,
                              void* d_out, int out_size, void* d_ws, size_t ws_size,
                              hipStream_t stream) {
  const float* x = (const float*)d_in[0];
  const int* mask = (const int*)d_in[1];
  const float* w_qkv = (const float*)d_in[2];
  const float* w_proj = (const float*)d_in[3];
  const float* b_proj = (const float*)d_in[4];
  float* out = (float*)d_out;

  char* ws = (char*)d_ws;
  u16* x_bf = (u16*)(ws + 0);              //  8192x384
  u16* wqkv_bf = (u16*)(ws + 6291456);     //  1152x384
  u16* wproj_bf = (u16*)(ws + 7176192);    //   384x384
  u16* q_bf = (u16*)(ws + 7471104);        //  [b,h,n,d]
  u16* k_bf = (u16*)(ws + 13762560);       //  [b,h,n,d]
  u16* vt_bf = (u16*)(ws + 20054016);      //  [b,h,d,n]
  u16* attn_bf = (u16*)(ws + 26345472);    //  8192x384
  float* madd = (float*)(ws + 32636928);   //  [2][4096] f32, ends 32669696
  float* o_part = (float*)(ws + 32669696); //  up to 4 x 8192x384 f32 = 50331648
  float* l_part4 = (float*)(ws + 83001344);//  4 x 12x4096 f32 = 786432; ends 83787776
  float* l_part2 = (float*)(ws + 57835520);//  2-way layout (R13); ends 58228736

  // fused prep: 3 casts + mask addend
  const int NPREP = 3145728 / 8 + 442368 / 8 + 147456 / 8 + 2 * NSEQ;
  prep_kernel<<<(NPREP + 255) / 256, 256, 0, stream>>>(x, w_qkv, w_proj, mask,
                                                       x_bf, wqkv_bf, wproj_bf, madd);

  gemm_bt<0><<<dim3(64, 9), 256, 0, stream>>>(x_bf, wqkv_bf, 384, 1152,
                                              q_bf, k_bf, vt_bf, nullptr, nullptr);

  if (ws_size >= 83787776) {
    attn_kernel32<4><<<1536, 256, 0, stream>>>(q_bf, k_bf, vt_bf, madd, o_part, l_part4);
    combine_kernel<4><<<3072, 256, 0, stream>>>(o_part, l_part4, attn_bf);
  } else if (ws_size >= 58228736) {
    attn_kernel32<2><<<768, 256, 0, stream>>>(q_bf, k_bf, vt_bf, madd, o_part, l_part2);
    combine_kernel<2><<<3072, 256, 0, stream>>>(o_part, l_part2, attn_bf);
  } else {
    attn_kernel16<<<dim3(64, 12), 256, 0, stream>>>(q_bf, k_bf, vt_bf, madd, attn_bf);
  }

  gemm_bt<1><<<dim3(64, 3), 256, 0, stream>>>(attn_bf, wproj_bf, 384, 384,
                                              nullptr, nullptr, nullptr, b_proj, out);
}

// Round 15
// 117.554 us; speedup vs baseline: 1.0420x; 1.0420x over previous
//
#include <hip/hip_runtime.h>
#include <cfloat>
#include <cstdint>
#include <cstddef>

using u16 = unsigned short;
typedef __attribute__((ext_vector_type(8))) short short8;
typedef __attribute__((ext_vector_type(4))) float f32x4;

#define HEADS 6
#define NSEQ 4096
#define SCALEF 0.125f
#define LOG2E 1.4426950408889634f
#define SC2 (SCALEF * LOG2E)

#if __has_builtin(__builtin_amdgcn_exp2f)
#define EXP2(x) __builtin_amdgcn_exp2f(x)
#else
#define EXP2(x) exp2f(x)
#endif

__device__ __forceinline__ u16 f2bf_rn(float f) {
  unsigned int u = __builtin_bit_cast(unsigned int, f);
  u = (u + 0x7FFFu + ((u >> 16) & 1u)) >> 16;
  return (u16)u;
}

__device__ __forceinline__ void gload_lds16(const void* g, void* l) {
  __builtin_amdgcn_global_load_lds((const __attribute__((address_space(1))) void*)g,
                                   (__attribute__((address_space(3))) void*)l, 16, 0, 0);
}

// Swizzled b128 read from a [rows][64] u16 LDS tile (128B rows). (GEMM use)
__device__ __forceinline__ short8 frag_read(const u16* tile, int row, int blk) {
  int byt = row * 128 + ((blk * 16) ^ ((row & 7) << 4));
  return *(const short8*)((const char*)tile + byt);
}

__device__ __forceinline__ void cast8(const float* __restrict__ s, u16* __restrict__ d, int i) {
  const float4* sp = (const float4*)s;
  float4 a = sp[2 * i], b = sp[2 * i + 1];
  short8 r;
  r[0] = (short)f2bf_rn(a.x); r[1] = (short)f2bf_rn(a.y);
  r[2] = (short)f2bf_rn(a.z); r[3] = (short)f2bf_rn(a.w);
  r[4] = (short)f2bf_rn(b.x); r[5] = (short)f2bf_rn(b.y);
  r[6] = (short)f2bf_rn(b.z); r[7] = (short)f2bf_rn(b.w);
  ((short8*)d)[i] = r;
}

// fused prep: cast x / w_qkv / w_proj to bf16 + mask -> float addend
__global__ void prep_kernel(const float* __restrict__ x, const float* __restrict__ wqkv,
                            const float* __restrict__ wproj, const int* __restrict__ mask,
                            u16* __restrict__ xb, u16* __restrict__ wqb, u16* __restrict__ wpb,
                            float* __restrict__ madd) {
  const int NX = 3145728 / 8, NQ = 442368 / 8, NP = 147456 / 8;
  int i = blockIdx.x * blockDim.x + threadIdx.x;
  if (i < NX) cast8(x, xb, i);
  else if (i < NX + NQ) cast8(wqkv, wqb, i - NX);
  else if (i < NX + NQ + NP) cast8(wproj, wpb, i - NX - NQ);
  else {
    int j = i - (NX + NQ + NP);
    if (j < 2 * NSEQ) madd[j] = mask[j] ? 0.f : -FLT_MAX;
  }
}

// C = A(MxK) * B(NxK)^T ; 128x128 tile, BK=64, 4 waves (2x2 of 64x64).
template <int EPI>
__launch_bounds__(256)
__global__ void gemm_bt(const u16* __restrict__ A, const u16* __restrict__ B,
                        int Kdim, int Ndim,
                        u16* __restrict__ q_out, u16* __restrict__ k_out, u16* __restrict__ vt_out,
                        const float* __restrict__ bias, float* __restrict__ out) {
  __shared__ u16 lA[128 * 64];
  __shared__ u16 lB[128 * 64];
  int brow = blockIdx.x, bcol = blockIdx.y;
  int tid = threadIdx.x;
  int w = tid >> 6, lane = tid & 63;
  int wr = w >> 1, wc = w & 1;
  int r_in = lane >> 3;
  int jblk = (lane & 7) ^ r_in;
  int l15 = lane & 15, lg = lane >> 4;

  f32x4 acc[4][4];
#pragma unroll
  for (int i = 0; i < 4; i++)
#pragma unroll
    for (int j = 0; j < 4; j++) acc[i][j] = (f32x4){0.f, 0.f, 0.f, 0.f};

  const u16* Ab = A + (size_t)(brow * 128 + w * 32 + r_in) * Kdim + jblk * 8;
  const u16* Bb = B + (size_t)(bcol * 128 + w * 32 + r_in) * Kdim + jblk * 8;

  int ksteps = Kdim >> 6;
  for (int kt = 0; kt < ksteps; ++kt) {
    __syncthreads();
#pragma unroll
    for (int c = 0; c < 4; ++c) {
      gload_lds16(Ab + kt * 64 + (size_t)(c * 8) * Kdim, &lA[(w * 32 + c * 8) * 64]);
      gload_lds16(Bb + kt * 64 + (size_t)(c * 8) * Kdim, &lB[(w * 32 + c * 8) * 64]);
    }
    asm volatile("s_waitcnt vmcnt(0)" ::: "memory");
    __syncthreads();

    short8 af[4][2], bfr[4][2];
#pragma unroll
    for (int ms = 0; ms < 4; ++ms)
#pragma unroll
      for (int hf = 0; hf < 2; ++hf)
        af[ms][hf] = frag_read(lA, wr * 64 + ms * 16 + l15, hf * 4 + lg);
#pragma unroll
    for (int ns = 0; ns < 4; ++ns)
#pragma unroll
      for (int hf = 0; hf < 2; ++hf)
        bfr[ns][hf] = frag_read(lB, wc * 64 + ns * 16 + l15, hf * 4 + lg);
#pragma unroll
    for (int ms = 0; ms < 4; ++ms)
#pragma unroll
      for (int ns = 0; ns < 4; ++ns) {
        acc[ms][ns] = __builtin_amdgcn_mfma_f32_16x16x32_bf16(af[ms][0], bfr[ns][0], acc[ms][ns], 0, 0, 0);
        acc[ms][ns] = __builtin_amdgcn_mfma_f32_16x16x32_bf16(af[ms][1], bfr[ns][1], acc[ms][ns], 0, 0, 0);
      }
  }

#pragma unroll
  for (int ms = 0; ms < 4; ++ms)
#pragma unroll
    for (int ns = 0; ns < 4; ++ns)
#pragma unroll
      for (int r = 0; r < 4; ++r) {
        int row_g = brow * 128 + wr * 64 + ms * 16 + lg * 4 + r;
        int col_g = bcol * 128 + wc * 64 + ns * 16 + l15;
        float v = acc[ms][ns][r];
        if (EPI == 0) {
          int t = col_g / 384;
          int rem = col_g - t * 384;
          int h = rem >> 6, d = rem & 63;
          int b = row_g >> 12, n = row_g & 4095;
          u16 val = f2bf_rn(v);
          size_t bh = (size_t)(b * HEADS + h);
          if (t == 0)      q_out[(bh * NSEQ + n) * 64 + d] = val;
          else if (t == 1) k_out[(bh * NSEQ + n) * 64 + d] = val;
          else             vt_out[(bh * 64 + d) * NSEQ + n] = val;
        } else {
          out[(size_t)row_g * Ndim + col_g] = v + bias[col_g];
        }
      }
}

// Flash attention, QBLK=32/wave, KT=64, streaming softmax, KS-way grid k-split,
// DOUBLE-BUFFERED LDS with stage-at-top: one barrier per tile, zero exposed
// vmcnt drain (the compiler's barrier-drain lands after a full compute phase).
template <int KS>
__launch_bounds__(256, 3)
__global__ void attn_kernel32(const u16* __restrict__ qg, const u16* __restrict__ kg,
                              const u16* __restrict__ vtg, const float* __restrict__ madd,
                              float* __restrict__ o_part, float* __restrict__ l_part) {
  __shared__ u16 lK[2][64 * 64];   // [buf][k_local][d], 128B rows, XOR key = row&7
  __shared__ u16 lV[2][64 * 64];   // [buf][d][k_local], 128B rows, XOR key = row&7

  // bijective XCD swizzle: 32*12*KS blocks, 48*KS per XCD; qb fastest
  int bid = blockIdx.x;
  int orig = (bid & 7) * (48 * KS) + (bid >> 3);
  int qb = orig & 31;
  int rr = orig >> 5;              // 0 .. 12*KS-1
  int bh = rr % 12, kh = rr / 12;
  int kbase = kh * (NSEQ / KS);
  const int NT = (NSEQ / KS) / 64;

  int b = bh / HEADS;
  int tid = threadIdx.x;
  int w = tid >> 6, lane = tid & 63;
  int l15 = lane & 15, lg = lane >> 4;
  int r_in = lane >> 3, jblk = (lane & 7) ^ r_in;

  const u16* Q = qg + (size_t)bh * NSEQ * 64;
  const u16* K = kg + (size_t)bh * NSEQ * 64;
  const u16* VT = vtg + (size_t)bh * 64 * NSEQ;
  const float* marow = madd + b * NSEQ;

  int q0 = qb * 128 + w * 32;
  int qrow0 = q0 + l15, qrow1 = q0 + 16 + l15;
  short8 qfA[2], qfB[2];
#pragma unroll
  for (int hf = 0; hf < 2; ++hf) {
    qfA[hf] = *(const short8*)(Q + (size_t)qrow0 * 64 + hf * 32 + lg * 8);
    qfB[hf] = *(const short8*)(Q + (size_t)qrow1 * 64 + hf * 32 + lg * 8);
  }

  float qsel0 = (marow[qrow0] == 0.0f) ? 1.0f : 0.0f;
  float qsel1 = (marow[qrow1] == 0.0f) ? 1.0f : 0.0f;
  float scq0 = SC2 * qsel0, scq1 = SC2 * qsel1;

  // lane-constant swizzled read offsets (row = x*16 + l15 -> row&7 == l15&7)
  int swk = (l15 & 7) << 4;
  int offKA = l15 * 128 + ((lg * 16) ^ swk);
  int offKB = l15 * 128 + (((4 + lg) * 16) ^ swk);

  f32x4 acc0[4], acc1[4];
#pragma unroll
  for (int ds_ = 0; ds_ < 4; ++ds_) {
    acc0[ds_] = (f32x4){0.f, 0.f, 0.f, 0.f};
    acc1[ds_] = (f32x4){0.f, 0.f, 0.f, 0.f};
  }
  f32x4 lsum0 = (f32x4){0.f, 0.f, 0.f, 0.f};
  f32x4 lsum1 = (f32x4){0.f, 0.f, 0.f, 0.f};

  // STAGE into buffer BUF (R2-proven dbuf pattern): linear dest + pre-swizzled source
#define STAGE(BUF, k0s)                                                                     \
  {                                                                                         \
    _Pragma("unroll")                                                                       \
    for (int c = 0; c < 2; ++c) {                                                           \
      int rowb = w * 16 + c * 8;                                                            \
      gload_lds16(K + (size_t)((k0s) + rowb + r_in) * 64 + jblk * 8, &lK[BUF][rowb * 64]);  \
      gload_lds16(VT + (size_t)(rowb + r_in) * NSEQ + (k0s) + jblk * 8, &lV[BUF][rowb * 64]);\
    }                                                                                       \
  }

  STAGE(0, kbase);
  asm volatile("s_waitcnt vmcnt(0)" ::: "memory");
  __syncthreads();

  int cur = 0;
  for (int t = 0; t < NT; ++t) {
    if (t + 1 < NT) STAGE(cur ^ 1, kbase + (t + 1) * 64);   // hidden under this tile's compute

    const char* kb = (const char*)lK[cur];
    const char* vb = (const char*)lV[cur];

    // S^T = K Q^T, both q-subtiles; kf read ONCE per cs
    f32x4 p0[4], p1[4];
    __builtin_amdgcn_s_setprio(1);
#pragma unroll
    for (int cs = 0; cs < 4; ++cs) {
      short8 kf0 = *(const short8*)(kb + offKA + cs * 2048);
      short8 kf1 = *(const short8*)(kb + offKB + cs * 2048);
      f32x4 z0 = (f32x4){0.f, 0.f, 0.f, 0.f};
      f32x4 z1 = (f32x4){0.f, 0.f, 0.f, 0.f};
      z0 = __builtin_amdgcn_mfma_f32_16x16x32_bf16(kf0, qfA[0], z0, 0, 0, 0);
      z1 = __builtin_amdgcn_mfma_f32_16x16x32_bf16(kf0, qfB[0], z1, 0, 0, 0);
      p0[cs] = __builtin_amdgcn_mfma_f32_16x16x32_bf16(kf1, qfA[1], z0, 0, 0, 0);
      p1[cs] = __builtin_amdgcn_mfma_f32_16x16x32_bf16(kf1, qfB[1], z1, 0, 0, 0);
    }
    __builtin_amdgcn_s_setprio(0);

    // streaming softmax; mask vector loaded once per cs
    int k0 = kbase + t * 64;
#pragma unroll
    for (int cs = 0; cs < 4; ++cs) {
      f32x4 mf = *(const f32x4*)(marow + k0 + cs * 16 + lg * 4);
      f32x4 d0 = p0[cs] * scq0 + mf * qsel0;
      f32x4 d1 = p1[cs] * scq1 + mf * qsel1;
#pragma unroll
      for (int r = 0; r < 4; ++r) {
        p0[cs][r] = EXP2(d0[r]);
        p1[cs][r] = EXP2(d1[r]);
      }
    }
    lsum0 += (p0[0] + p0[1]) + (p0[2] + p0[3]);
    lsum1 += (p1[0] + p1[1]) + (p1[2] + p1[3]);

    // dance: subtile A then B (keeps transient wd-state small)
    short8 pfA[2], pfB[2];
    {
      uint32_t wd[4][2];
#pragma unroll
      for (int cs = 0; cs < 4; ++cs)
#pragma unroll
        for (int hh = 0; hh < 2; ++hh)
          asm("v_cvt_pk_bf16_f32 %0, %1, %2" : "=v"(wd[cs][hh]) : "v"(p0[cs][2 * hh]), "v"(p0[cs][2 * hh + 1]));
#pragma unroll
      for (int c = 0; c < 2; ++c) {
        union { uint32_t u[4]; short8 s8; } cv;
#pragma unroll
        for (int hh = 0; hh < 2; ++hh) {
          uint32_t A = wd[2 * c][hh], B = wd[2 * c + 1][hh];
          asm("v_permlane32_swap_b32 %0, %1" : "+v"(A), "+v"(B));
          asm("v_permlane16_swap_b32 %0, %1" : "+v"(A), "+v"(B));
          cv.u[hh] = A;
          cv.u[2 + hh] = B;
        }
        pfA[c] = cv.s8;
      }
    }
    {
      uint32_t wd[4][2];
#pragma unroll
      for (int cs = 0; cs < 4; ++cs)
#pragma unroll
        for (int hh = 0; hh < 2; ++hh)
          asm("v_cvt_pk_bf16_f32 %0, %1, %2" : "=v"(wd[cs][hh]) : "v"(p1[cs][2 * hh]), "v"(p1[cs][2 * hh + 1]));
#pragma unroll
      for (int c = 0; c < 2; ++c) {
        union { uint32_t u[4]; short8 s8; } cv;
#pragma unroll
        for (int hh = 0; hh < 2; ++hh) {
          uint32_t A = wd[2 * c][hh], B = wd[2 * c + 1][hh];
          asm("v_permlane32_swap_b32 %0, %1" : "+v"(A), "+v"(B));
          asm("v_permlane16_swap_b32 %0, %1" : "+v"(A), "+v"(B));
          cv.u[hh] = A;
          cv.u[2 + hh] = B;
        }
        pfB[c] = cv.s8;
      }
    }

    // O^T += V^T P^T ; vf read ONCE per ds
    __builtin_amdgcn_s_setprio(1);
#pragma unroll
    for (int ds_ = 0; ds_ < 4; ++ds_) {
      short8 vf0 = *(const short8*)(vb + offKA + ds_ * 2048);
      short8 vf1 = *(const short8*)(vb + offKB + ds_ * 2048);
      acc0[ds_] = __builtin_amdgcn_mfma_f32_16x16x32_bf16(vf0, pfA[0], acc0[ds_], 0, 0, 0);
      acc0[ds_] = __builtin_amdgcn_mfma_f32_16x16x32_bf16(vf1, pfA[1], acc0[ds_], 0, 0, 0);
      acc1[ds_] = __builtin_amdgcn_mfma_f32_16x16x32_bf16(vf0, pfB[0], acc1[ds_], 0, 0, 0);
      acc1[ds_] = __builtin_amdgcn_mfma_f32_16x16x32_bf16(vf1, pfB[1], acc1[ds_], 0, 0, 0);
    }
    __builtin_amdgcn_s_setprio(0);

    __syncthreads();   // single barrier: drains stage(t+1) loads (already landed) + LDS reads
    cur ^= 1;
  }

  float rsum0 = (lsum0[0] + lsum0[1]) + (lsum0[2] + lsum0[3]);
  rsum0 += __shfl_xor(rsum0, 16);
  rsum0 += __shfl_xor(rsum0, 32);
  float rsum1 = (lsum1[0] + lsum1[1]) + (lsum1[2] + lsum1[3]);
  rsum1 += __shfl_xor(rsum1, 16);
  rsum1 += __shfl_xor(rsum1, 32);

  float* op = o_part + (size_t)kh * (8192ull * 384);
  int hd = bh - b * HEADS;
  size_t base0 = ((size_t)b * NSEQ + qrow0) * 384 + hd * 64;
  size_t base1 = ((size_t)b * NSEQ + qrow1) * 384 + hd * 64;
#pragma unroll
  for (int ds_ = 0; ds_ < 4; ++ds_) {
    *(f32x4*)(op + base0 + ds_ * 16 + lg * 4) = acc0[ds_];
    *(f32x4*)(op + base1 + ds_ * 16 + lg * 4) = acc1[ds_];
  }
  if (lg == 0) {
    l_part[(kh * 12 + bh) * NSEQ + qrow0] = rsum0;
    l_part[(kh * 12 + bh) * NSEQ + qrow1] = rsum1;
  }
#undef STAGE
}

// Fallback (R10-proven): QBLK=16, KT=128, no split, bf16 out directly.
__launch_bounds__(256, 3)
__global__ void attn_kernel16(const u16* __restrict__ qg, const u16* __restrict__ kg,
                              const u16* __restrict__ vtg, const float* __restrict__ madd,
                              u16* __restrict__ attn_out) {
  __shared__ u16 lK[128 * 64];
  __shared__ u16 lV[64 * 128];
  int bid = blockIdx.y * 64 + blockIdx.x;
  int orig = (bid & 7) * 96 + (bid >> 3);
  int qb = orig & 63, bh = orig >> 6;
  int b = bh / HEADS, hd = bh - b * HEADS;
  int q0 = qb * 64;
  int tid = threadIdx.x;
  int w = tid >> 6, lane = tid & 63;
  int l15 = lane & 15, lg = lane >> 4;
  int r_in = lane >> 3, jblk = (lane & 7) ^ r_in;
  const u16* Q = qg + (size_t)bh * NSEQ * 64;
  const u16* K = kg + (size_t)bh * NSEQ * 64;
  const u16* VT = vtg + (size_t)bh * 64 * NSEQ;
  const float* marow = madd + b * NSEQ;
  int qrow = q0 + w * 16 + l15;
  short8 qf[2];
#pragma unroll
  for (int hf = 0; hf < 2; ++hf)
    qf[hf] = *(const short8*)(Q + (size_t)qrow * 64 + hf * 32 + lg * 8);
  float qsel = (marow[qrow] == 0.0f) ? 1.0f : 0.0f;
  float scq = SC2 * qsel;
  int swk = (l15 & 7) << 4;
  int offKA = l15 * 128 + ((lg * 16) ^ swk);
  int offKB = l15 * 128 + (((4 + lg) * 16) ^ swk);
  int voff[4];
#pragma unroll
  for (int c = 0; c < 4; ++c) voff[c] = l15 * 256 + ((((c * 4 + lg) ^ l15)) << 4);
  f32x4 acc[4];
#pragma unroll
  for (int ds_ = 0; ds_ < 4; ++ds_) acc[ds_] = (f32x4){0.f, 0.f, 0.f, 0.f};
  f32x4 lsum = (f32x4){0.f, 0.f, 0.f, 0.f};
#define STAGE(k0s)                                                                    \
  {                                                                                   \
    _Pragma("unroll")                                                                 \
    for (int c = 0; c < 4; ++c) {                                                     \
      int krb = w * 32 + c * 8;                                                       \
      gload_lds16(K + (size_t)((k0s) + krb + r_in) * 64 + jblk * 8, &lK[krb * 64]);   \
      int vrb = w * 16 + c * 4;                                                       \
      int vsb = l15 ^ (c * 4 + lg);                                                   \
      gload_lds16(VT + (size_t)(vrb + lg) * NSEQ + (k0s) + vsb * 8, &lV[vrb * 128]);  \
    }                                                                                 \
  }
  STAGE(0);
  asm volatile("s_waitcnt vmcnt(0)" ::: "memory");
  __syncthreads();
  const int NT = NSEQ / 128;
  for (int t = 0; t < NT; ++t) {
    int k0 = t * 128;
    f32x4 p[8];
    __builtin_amdgcn_s_setprio(1);
#pragma unroll
    for (int cs = 0; cs < 8; ++cs) {
      short8 kf0 = *(const short8*)((const char*)lK + offKA + cs * 2048);
      short8 kf1 = *(const short8*)((const char*)lK + offKB + cs * 2048);
      f32x4 z = (f32x4){0.f, 0.f, 0.f, 0.f};
      z = __builtin_amdgcn_mfma_f32_16x16x32_bf16(kf0, qf[0], z, 0, 0, 0);
      p[cs] = __builtin_amdgcn_mfma_f32_16x16x32_bf16(kf1, qf[1], z, 0, 0, 0);
    }
    __builtin_amdgcn_s_setprio(0);
#pragma unroll
    for (int cs = 0; cs < 8; ++cs) {
      f32x4 mf = *(const f32x4*)(marow + k0 + cs * 16 + lg * 4);
      f32x4 d = p[cs] * scq + mf * qsel;
#pragma unroll
      for (int r = 0; r < 4; ++r) p[cs][r] = EXP2(d[r]);
    }
    lsum += ((p[0] + p[1]) + (p[2] + p[3])) + ((p[4] + p[5]) + (p[6] + p[7]));
    uint32_t wd[8][2];
#pragma unroll
    for (int cs = 0; cs < 8; ++cs)
#pragma unroll
      for (int hh = 0; hh < 2; ++hh)
        asm("v_cvt_pk_bf16_f32 %0, %1, %2" : "=v"(wd[cs][hh]) : "v"(p[cs][2 * hh]), "v"(p[cs][2 * hh + 1]));
    short8 pf[4];
#pragma unroll
    for (int c = 0; c < 4; ++c) {
      union { uint32_t u[4]; short8 s8; } cv;
#pragma unroll
      for (int hh = 0; hh < 2; ++hh) {
        uint32_t A = wd[2 * c][hh], B = wd[2 * c + 1][hh];
        asm("v_permlane32_swap_b32 %0, %1" : "+v"(A), "+v"(B));
        asm("v_permlane16_swap_b32 %0, %1" : "+v"(A), "+v"(B));
        cv.u[hh] = A;
        cv.u[2 + hh] = B;
      }
      pf[c] = cv.s8;
    }
    __builtin_amdgcn_s_setprio(1);
#pragma unroll
    for (int ds_ = 0; ds_ < 4; ++ds_)
#pragma unroll
      for (int c = 0; c < 4; ++c) {
        short8 vf = *(const short8*)((const char*)lV + voff[c] + ds_ * 4096);
        acc[ds_] = __builtin_amdgcn_mfma_f32_16x16x32_bf16(vf, pf[c], acc[ds_], 0, 0, 0);
      }
    __builtin_amdgcn_s_setprio(0);
    __syncthreads();
    if (t + 1 < NT) {
      STAGE(k0 + 128);
      asm volatile("s_waitcnt vmcnt(0)" ::: "memory");
      __syncthreads();
    }
  }
  float rsum = (lsum[0] + lsum[1]) + (lsum[2] + lsum[3]);
  rsum += __shfl_xor(rsum, 16);
  rsum += __shfl_xor(rsum, 32);
  float inv = 1.0f / rsum;
  size_t base = ((size_t)b * NSEQ + qrow) * 384 + hd * 64;
#pragma unroll
  for (int ds_ = 0; ds_ < 4; ++ds_) {
    uint32_t w0, w1;
    float a0 = acc[ds_][0] * inv, a1 = acc[ds_][1] * inv;
    float a2 = acc[ds_][2] * inv, a3 = acc[ds_][3] * inv;
    asm("v_cvt_pk_bf16_f32 %0, %1, %2" : "=v"(w0) : "v"(a0), "v"(a1));
    asm("v_cvt_pk_bf16_f32 %0, %1, %2" : "=v"(w1) : "v"(a2), "v"(a3));
    uint2 st; st.x = w0; st.y = w1;
    *(uint2*)(attn_out + base + ds_ * 16 + lg * 4) = st;
  }
#undef STAGE
}

// combine KS k-split partials: out = (sum O_kh) / (sum l_kh), cast bf16
template <int KS>
__global__ void combine_kernel(const float* __restrict__ o_part, const float* __restrict__ l_part,
                               u16* __restrict__ out) {
  int i = blockIdx.x * blockDim.x + threadIdx.x;   // float4 index, 786432 total
  int elem = i * 4;
  int ng = elem / 384;
  int cc = elem - ng * 384;
  int h = cc >> 6;
  int b = ng >> 12, n = ng & 4095;
  int li = (b * HEADS + h) * NSEQ + n;

  float4 a = ((const float4*)o_part)[i];
  float lt = l_part[li];
#pragma unroll
  for (int kh = 1; kh < KS; ++kh) {
    float4 c = ((const float4*)(o_part + (size_t)kh * (8192ull * 384)))[i];
    a.x += c.x; a.y += c.y; a.z += c.z; a.w += c.w;
    lt += l_part[kh * 12 * NSEQ + li];
  }
  float inv = 1.0f / lt;
  float a0 = a.x * inv, a1 = a.y * inv, a2 = a.z * inv, a3 = a.w * inv;
  uint32_t w0, w1;
  asm("v_cvt_pk_bf16_f32 %0, %1, %2" : "=v"(w0) : "v"(a0), "v"(a1));
  asm("v_cvt_pk_bf16_f32 %0, %1, %2" : "=v"(w1) : "v"(a2), "v"(a3));
  uint2 st; st.x = w0; st.y = w1;
  *(uint2*)(out + elem) = st;
}

extern "C" void kernel_launch(void* const* d_in, const int* in_sizes, int n_in,
                              void* d_out, int out_size, void* d_ws, size_t ws_size,
                              hipStream_t stream) {
  const float* x = (const float*)d_in[0];
  const int* mask = (const int*)d_in[1];
  const float* w_qkv = (const float*)d_in[2];
  const float* w_proj = (const float*)d_in[3];
  const float* b_proj = (const float*)d_in[4];
  float* out = (float*)d_out;

  char* ws = (char*)d_ws;
  u16* x_bf = (u16*)(ws + 0);              //  8192x384
  u16* wqkv_bf = (u16*)(ws + 6291456);     //  1152x384
  u16* wproj_bf = (u16*)(ws + 7176192);    //   384x384
  u16* q_bf = (u16*)(ws + 7471104);        //  [b,h,n,d]
  u16* k_bf = (u16*)(ws + 13762560);       //  [b,h,n,d]
  u16* vt_bf = (u16*)(ws + 20054016);      //  [b,h,d,n]
  u16* attn_bf = (u16*)(ws + 26345472);    //  8192x384
  float* madd = (float*)(ws + 32636928);   //  [2][4096] f32, ends 32669696
  float* o_part = (float*)(ws + 32669696); //  2 x 8192x384 f32 = 25165824
  float* l_part = (float*)(ws + 57835520); //  2 x 12x4096 f32 = 393216; ends 58228736

  // fused prep: 3 casts + mask addend
  const int NPREP = 3145728 / 8 + 442368 / 8 + 147456 / 8 + 2 * NSEQ;
  prep_kernel<<<(NPREP + 255) / 256, 256, 0, stream>>>(x, w_qkv, w_proj, mask,
                                                       x_bf, wqkv_bf, wproj_bf, madd);

  gemm_bt<0><<<dim3(64, 9), 256, 0, stream>>>(x_bf, wqkv_bf, 384, 1152,
                                              q_bf, k_bf, vt_bf, nullptr, nullptr);

  if (ws_size >= 58228736) {
    attn_kernel32<2><<<768, 256, 0, stream>>>(q_bf, k_bf, vt_bf, madd, o_part, l_part);
    combine_kernel<2><<<3072, 256, 0, stream>>>(o_part, l_part, attn_bf);
  } else {
    attn_kernel16<<<dim3(64, 12), 256, 0, stream>>>(q_bf, k_bf, vt_bf, madd, attn_bf);
  }

  gemm_bt<1><<<dim3(64, 3), 256, 0, stream>>>(attn_bf, wproj_bf, 384, 384,
                                              nullptr, nullptr, nullptr, b_proj, out);
}

// Round 16
// 109.201 us; speedup vs baseline: 1.1217x; 1.0765x over previous
//
#include <hip/hip_runtime.h>
#include <cfloat>
#include <cstdint>
#include <cstddef>

using u16 = unsigned short;
typedef __attribute__((ext_vector_type(8))) short short8;
typedef __attribute__((ext_vector_type(4))) float f32x4;

#define HEADS 6
#define NSEQ 4096
#define SCALEF 0.125f
#define LOG2E 1.4426950408889634f
#define SC2 (SCALEF * LOG2E)

#if __has_builtin(__builtin_amdgcn_exp2f)
#define EXP2(x) __builtin_amdgcn_exp2f(x)
#else
#define EXP2(x) exp2f(x)
#endif

__device__ __forceinline__ u16 f2bf_rn(float f) {
  unsigned int u = __builtin_bit_cast(unsigned int, f);
  u = (u + 0x7FFFu + ((u >> 16) & 1u)) >> 16;
  return (u16)u;
}

__device__ __forceinline__ void gload_lds16(const void* g, void* l) {
  __builtin_amdgcn_global_load_lds((const __attribute__((address_space(1))) void*)g,
                                   (__attribute__((address_space(3))) void*)l, 16, 0, 0);
}

// Swizzled b128 read from a [rows][64] u16 LDS tile (128B rows). (GEMM use)
__device__ __forceinline__ short8 frag_read(const u16* tile, int row, int blk) {
  int byt = row * 128 + ((blk * 16) ^ ((row & 7) << 4));
  return *(const short8*)((const char*)tile + byt);
}

__device__ __forceinline__ void cast8(const float* __restrict__ s, u16* __restrict__ d, int i) {
  const float4* sp = (const float4*)s;
  float4 a = sp[2 * i], b = sp[2 * i + 1];
  short8 r;
  r[0] = (short)f2bf_rn(a.x); r[1] = (short)f2bf_rn(a.y);
  r[2] = (short)f2bf_rn(a.z); r[3] = (short)f2bf_rn(a.w);
  r[4] = (short)f2bf_rn(b.x); r[5] = (short)f2bf_rn(b.y);
  r[6] = (short)f2bf_rn(b.z); r[7] = (short)f2bf_rn(b.w);
  ((short8*)d)[i] = r;
}

// fused prep: cast x / w_qkv / w_proj to bf16 + mask -> float addend
__global__ void prep_kernel(const float* __restrict__ x, const float* __restrict__ wqkv,
                            const float* __restrict__ wproj, const int* __restrict__ mask,
                            u16* __restrict__ xb, u16* __restrict__ wqb, u16* __restrict__ wpb,
                            float* __restrict__ madd) {
  const int NX = 3145728 / 8, NQ = 442368 / 8, NP = 147456 / 8;
  int i = blockIdx.x * blockDim.x + threadIdx.x;
  if (i < NX) cast8(x, xb, i);
  else if (i < NX + NQ) cast8(wqkv, wqb, i - NX);
  else if (i < NX + NQ + NP) cast8(wproj, wpb, i - NX - NQ);
  else {
    int j = i - (NX + NQ + NP);
    if (j < 2 * NSEQ) madd[j] = mask[j] ? 0.f : -FLT_MAX;
  }
}

// Deterministic mask compaction (order-preserving permutation).
// cpos[b][n]: permuted position (unmasked k first, then masked).
// acm[b][j]: 0 for j < nc (unmasked), -FLT_MAX otherwise.
// nth[b]: 64-tiles per k-half = ceil(nc/128).
__global__ void compact_kernel(const int* __restrict__ mask, int* __restrict__ cpos,
                               float* __restrict__ acm, int* __restrict__ nth) {
  __shared__ int cnt[256];
  __shared__ int offu[256];
  __shared__ int s_nc;
  int b = blockIdx.x;
  int t = threadIdx.x;
  const int* m = mask + b * NSEQ;
  int base = t * 16;
  int c = 0;
#pragma unroll
  for (int i = 0; i < 16; ++i) c += (m[base + i] != 0) ? 1 : 0;
  cnt[t] = c;
  __syncthreads();
  if (t == 0) {
    int s = 0;
    for (int i = 0; i < 256; ++i) { offu[i] = s; s += cnt[i]; }
    s_nc = s;
    int ncpad = (s + 127) & ~127;
    if (ncpad == 0) ncpad = 128;
    nth[b] = ncpad / 128;
  }
  __syncthreads();
  int nc = s_nc;
  int ou = offu[t];
  int om = base - ou;
  for (int i = 0; i < 16; ++i) {
    int n = base + i;
    int um = (m[n] != 0) ? 1 : 0;
    int pos = um ? ou : (nc + om);
    ou += um;
    om += 1 - um;
    cpos[b * NSEQ + n] = pos;
    acm[b * NSEQ + pos] = um ? 0.f : -FLT_MAX;
  }
}

// meanV[bh*64+d] = mean over all 4096 k of V (from permuted VT — sum invariant)
__global__ void meanv_kernel(const u16* __restrict__ vt, float* __restrict__ meanv) {
  int row = blockIdx.x;   // 768 = 12 bh * 64 d
  const u16* src = vt + (size_t)row * NSEQ + threadIdx.x * 8;
  float s = 0.f;
#pragma unroll
  for (int i = 0; i < 8; ++i) {
    short8 v = *(const short8*)(src + i * 512);
#pragma unroll
    for (int j = 0; j < 8; ++j) {
      unsigned int u = ((unsigned int)(unsigned short)v[j]) << 16;
      s += __builtin_bit_cast(float, u);
    }
  }
#pragma unroll
  for (int off = 1; off < 64; off <<= 1) s += __shfl_xor(s, off);
  if (threadIdx.x == 0) meanv[row] = s * (1.0f / NSEQ);
}

// C = A(MxK) * B(NxK)^T ; 128x128 tile, BK=64, 4 waves (2x2 of 64x64).
// EPI 0 scatters k/vt in PERMUTED order via cpos (q unpermuted).
template <int EPI>
__launch_bounds__(256)
__global__ void gemm_bt(const u16* __restrict__ A, const u16* __restrict__ B,
                        int Kdim, int Ndim,
                        u16* __restrict__ q_out, u16* __restrict__ k_out, u16* __restrict__ vt_out,
                        const int* __restrict__ cpos,
                        const float* __restrict__ bias, float* __restrict__ out) {
  __shared__ u16 lA[128 * 64];
  __shared__ u16 lB[128 * 64];
  int brow = blockIdx.x, bcol = blockIdx.y;
  int tid = threadIdx.x;
  int w = tid >> 6, lane = tid & 63;
  int wr = w >> 1, wc = w & 1;
  int r_in = lane >> 3;
  int jblk = (lane & 7) ^ r_in;
  int l15 = lane & 15, lg = lane >> 4;

  f32x4 acc[4][4];
#pragma unroll
  for (int i = 0; i < 4; i++)
#pragma unroll
    for (int j = 0; j < 4; j++) acc[i][j] = (f32x4){0.f, 0.f, 0.f, 0.f};

  const u16* Ab = A + (size_t)(brow * 128 + w * 32 + r_in) * Kdim + jblk * 8;
  const u16* Bb = B + (size_t)(bcol * 128 + w * 32 + r_in) * Kdim + jblk * 8;

  int ksteps = Kdim >> 6;
  for (int kt = 0; kt < ksteps; ++kt) {
    __syncthreads();
#pragma unroll
    for (int c = 0; c < 4; ++c) {
      gload_lds16(Ab + kt * 64 + (size_t)(c * 8) * Kdim, &lA[(w * 32 + c * 8) * 64]);
      gload_lds16(Bb + kt * 64 + (size_t)(c * 8) * Kdim, &lB[(w * 32 + c * 8) * 64]);
    }
    asm volatile("s_waitcnt vmcnt(0)" ::: "memory");
    __syncthreads();

    short8 af[4][2], bfr[4][2];
#pragma unroll
    for (int ms = 0; ms < 4; ++ms)
#pragma unroll
      for (int hf = 0; hf < 2; ++hf)
        af[ms][hf] = frag_read(lA, wr * 64 + ms * 16 + l15, hf * 4 + lg);
#pragma unroll
    for (int ns = 0; ns < 4; ++ns)
#pragma unroll
      for (int hf = 0; hf < 2; ++hf)
        bfr[ns][hf] = frag_read(lB, wc * 64 + ns * 16 + l15, hf * 4 + lg);
#pragma unroll
    for (int ms = 0; ms < 4; ++ms)
#pragma unroll
      for (int ns = 0; ns < 4; ++ns) {
        acc[ms][ns] = __builtin_amdgcn_mfma_f32_16x16x32_bf16(af[ms][0], bfr[ns][0], acc[ms][ns], 0, 0, 0);
        acc[ms][ns] = __builtin_amdgcn_mfma_f32_16x16x32_bf16(af[ms][1], bfr[ns][1], acc[ms][ns], 0, 0, 0);
      }
  }

#pragma unroll
  for (int ms = 0; ms < 4; ++ms)
#pragma unroll
    for (int ns = 0; ns < 4; ++ns)
#pragma unroll
      for (int r = 0; r < 4; ++r) {
        int row_g = brow * 128 + wr * 64 + ms * 16 + lg * 4 + r;
        int col_g = bcol * 128 + wc * 64 + ns * 16 + l15;
        float v = acc[ms][ns][r];
        if (EPI == 0) {
          int t = col_g / 384;
          int rem = col_g - t * 384;
          int h = rem >> 6, d = rem & 63;
          int b = row_g >> 12, n = row_g & 4095;
          u16 val = f2bf_rn(v);
          size_t bh = (size_t)(b * HEADS + h);
          if (t == 0) {
            q_out[(bh * NSEQ + n) * 64 + d] = val;
          } else {
            int pp = cpos[row_g];            // permuted k-position
            if (t == 1) k_out[(bh * NSEQ + pp) * 64 + d] = val;
            else        vt_out[(bh * 64 + d) * NSEQ + pp] = val;
          }
        } else {
          out[(size_t)row_g * Ndim + col_g] = v + bias[col_g];
        }
      }
}

// Flash attention over COMPACTED k, QBLK=32/wave, KT=64, streaming softmax,
// KS-way grid k-split, double-buffered LDS (R15-proven core; only NT/kbase
// runtime + k-addend from acm differ).
template <int KS>
__launch_bounds__(256, 3)
__global__ void attn_kernel32(const u16* __restrict__ qg, const u16* __restrict__ kg,
                              const u16* __restrict__ vtg, const float* __restrict__ madd,
                              const float* __restrict__ acm, const int* __restrict__ nth,
                              float* __restrict__ o_part, float* __restrict__ l_part) {
  __shared__ u16 lK[2][64 * 64];   // [buf][k_local][d], 128B rows, XOR key = row&7
  __shared__ u16 lV[2][64 * 64];   // [buf][d][k_local], 128B rows, XOR key = row&7

  // bijective XCD swizzle: 32*12*KS blocks, 48*KS per XCD; qb fastest
  int bid = blockIdx.x;
  int orig = (bid & 7) * (48 * KS) + (bid >> 3);
  int qb = orig & 31;
  int rr = orig >> 5;              // 0 .. 12*KS-1
  int bh = rr % 12, kh = rr / 12;

  int b = bh / HEADS;
  const int NT = nth[b];           // 64-tiles per k-half (compacted)
  int kbase = kh * NT * 64;

  int tid = threadIdx.x;
  int w = tid >> 6, lane = tid & 63;
  int l15 = lane & 15, lg = lane >> 4;
  int r_in = lane >> 3, jblk = (lane & 7) ^ r_in;

  const u16* Q = qg + (size_t)bh * NSEQ * 64;
  const u16* K = kg + (size_t)bh * NSEQ * 64;
  const u16* VT = vtg + (size_t)bh * 64 * NSEQ;
  const float* marow = madd + b * NSEQ;   // q-mask addend (original order)
  const float* acrow = acm + b * NSEQ;    // k-mask addend (permuted order)

  int q0 = qb * 128 + w * 32;
  int qrow0 = q0 + l15, qrow1 = q0 + 16 + l15;
  short8 qfA[2], qfB[2];
#pragma unroll
  for (int hf = 0; hf < 2; ++hf) {
    qfA[hf] = *(const short8*)(Q + (size_t)qrow0 * 64 + hf * 32 + lg * 8);
    qfB[hf] = *(const short8*)(Q + (size_t)qrow1 * 64 + hf * 32 + lg * 8);
  }

  float qsel0 = (marow[qrow0] == 0.0f) ? 1.0f : 0.0f;
  float qsel1 = (marow[qrow1] == 0.0f) ? 1.0f : 0.0f;
  float scq0 = SC2 * qsel0, scq1 = SC2 * qsel1;

  // lane-constant swizzled read offsets (row = x*16 + l15 -> row&7 == l15&7)
  int swk = (l15 & 7) << 4;
  int offKA = l15 * 128 + ((lg * 16) ^ swk);
  int offKB = l15 * 128 + (((4 + lg) * 16) ^ swk);

  f32x4 acc0[4], acc1[4];
#pragma unroll
  for (int ds_ = 0; ds_ < 4; ++ds_) {
    acc0[ds_] = (f32x4){0.f, 0.f, 0.f, 0.f};
    acc1[ds_] = (f32x4){0.f, 0.f, 0.f, 0.f};
  }
  f32x4 lsum0 = (f32x4){0.f, 0.f, 0.f, 0.f};
  f32x4 lsum1 = (f32x4){0.f, 0.f, 0.f, 0.f};

  // STAGE into buffer BUF (proven dbuf pattern): linear dest + pre-swizzled source
#define STAGE(BUF, k0s)                                                                     \
  {                                                                                         \
    _Pragma("unroll")                                                                       \
    for (int c = 0; c < 2; ++c) {                                                           \
      int rowb = w * 16 + c * 8;                                                            \
      gload_lds16(K + (size_t)((k0s) + rowb + r_in) * 64 + jblk * 8, &lK[BUF][rowb * 64]);  \
      gload_lds16(VT + (size_t)(rowb + r_in) * NSEQ + (k0s) + jblk * 8, &lV[BUF][rowb * 64]);\
    }                                                                                       \
  }

  STAGE(0, kbase);
  asm volatile("s_waitcnt vmcnt(0)" ::: "memory");
  __syncthreads();

  int cur = 0;
  for (int t = 0; t < NT; ++t) {
    if (t + 1 < NT) STAGE(cur ^ 1, kbase + (t + 1) * 64);

    const char* kb = (const char*)lK[cur];
    const char* vb = (const char*)lV[cur];

    // S^T = K Q^T, both q-subtiles; kf read ONCE per cs
    f32x4 p0[4], p1[4];
    __builtin_amdgcn_s_setprio(1);
#pragma unroll
    for (int cs = 0; cs < 4; ++cs) {
      short8 kf0 = *(const short8*)(kb + offKA + cs * 2048);
      short8 kf1 = *(const short8*)(kb + offKB + cs * 2048);
      f32x4 z0 = (f32x4){0.f, 0.f, 0.f, 0.f};
      f32x4 z1 = (f32x4){0.f, 0.f, 0.f, 0.f};
      z0 = __builtin_amdgcn_mfma_f32_16x16x32_bf16(kf0, qfA[0], z0, 0, 0, 0);
      z1 = __builtin_amdgcn_mfma_f32_16x16x32_bf16(kf0, qfB[0], z1, 0, 0, 0);
      p0[cs] = __builtin_amdgcn_mfma_f32_16x16x32_bf16(kf1, qfA[1], z0, 0, 0, 0);
      p1[cs] = __builtin_amdgcn_mfma_f32_16x16x32_bf16(kf1, qfB[1], z1, 0, 0, 0);
    }
    __builtin_amdgcn_s_setprio(0);

    // streaming softmax; compacted k-addend loaded once per cs
    int k0 = kbase + t * 64;
#pragma unroll
    for (int cs = 0; cs < 4; ++cs) {
      f32x4 mf = *(const f32x4*)(acrow + k0 + cs * 16 + lg * 4);
      f32x4 d0 = p0[cs] * scq0 + mf * qsel0;
      f32x4 d1 = p1[cs] * scq1 + mf * qsel1;
#pragma unroll
      for (int r = 0; r < 4; ++r) {
        p0[cs][r] = EXP2(d0[r]);
        p1[cs][r] = EXP2(d1[r]);
      }
    }
    lsum0 += (p0[0] + p0[1]) + (p0[2] + p0[3]);
    lsum1 += (p1[0] + p1[1]) + (p1[2] + p1[3]);

    // dance: subtile A then B
    short8 pfA[2], pfB[2];
    {
      uint32_t wd[4][2];
#pragma unroll
      for (int cs = 0; cs < 4; ++cs)
#pragma unroll
        for (int hh = 0; hh < 2; ++hh)
          asm("v_cvt_pk_bf16_f32 %0, %1, %2" : "=v"(wd[cs][hh]) : "v"(p0[cs][2 * hh]), "v"(p0[cs][2 * hh + 1]));
#pragma unroll
      for (int c = 0; c < 2; ++c) {
        union { uint32_t u[4]; short8 s8; } cv;
#pragma unroll
        for (int hh = 0; hh < 2; ++hh) {
          uint32_t A = wd[2 * c][hh], B = wd[2 * c + 1][hh];
          asm("v_permlane32_swap_b32 %0, %1" : "+v"(A), "+v"(B));
          asm("v_permlane16_swap_b32 %0, %1" : "+v"(A), "+v"(B));
          cv.u[hh] = A;
          cv.u[2 + hh] = B;
        }
        pfA[c] = cv.s8;
      }
    }
    {
      uint32_t wd[4][2];
#pragma unroll
      for (int cs = 0; cs < 4; ++cs)
#pragma unroll
        for (int hh = 0; hh < 2; ++hh)
          asm("v_cvt_pk_bf16_f32 %0, %1, %2" : "=v"(wd[cs][hh]) : "v"(p1[cs][2 * hh]), "v"(p1[cs][2 * hh + 1]));
#pragma unroll
      for (int c = 0; c < 2; ++c) {
        union { uint32_t u[4]; short8 s8; } cv;
#pragma unroll
        for (int hh = 0; hh < 2; ++hh) {
          uint32_t A = wd[2 * c][hh], B = wd[2 * c + 1][hh];
          asm("v_permlane32_swap_b32 %0, %1" : "+v"(A), "+v"(B));
          asm("v_permlane16_swap_b32 %0, %1" : "+v"(A), "+v"(B));
          cv.u[hh] = A;
          cv.u[2 + hh] = B;
        }
        pfB[c] = cv.s8;
      }
    }

    // O^T += V^T P^T ; vf read ONCE per ds
    __builtin_amdgcn_s_setprio(1);
#pragma unroll
    for (int ds_ = 0; ds_ < 4; ++ds_) {
      short8 vf0 = *(const short8*)(vb + offKA + ds_ * 2048);
      short8 vf1 = *(const short8*)(vb + offKB + ds_ * 2048);
      acc0[ds_] = __builtin_amdgcn_mfma_f32_16x16x32_bf16(vf0, pfA[0], acc0[ds_], 0, 0, 0);
      acc0[ds_] = __builtin_amdgcn_mfma_f32_16x16x32_bf16(vf1, pfA[1], acc0[ds_], 0, 0, 0);
      acc1[ds_] = __builtin_amdgcn_mfma_f32_16x16x32_bf16(vf0, pfB[0], acc1[ds_], 0, 0, 0);
      acc1[ds_] = __builtin_amdgcn_mfma_f32_16x16x32_bf16(vf1, pfB[1], acc1[ds_], 0, 0, 0);
    }
    __builtin_amdgcn_s_setprio(0);

    __syncthreads();
    cur ^= 1;
  }

  float rsum0 = (lsum0[0] + lsum0[1]) + (lsum0[2] + lsum0[3]);
  rsum0 += __shfl_xor(rsum0, 16);
  rsum0 += __shfl_xor(rsum0, 32);
  float rsum1 = (lsum1[0] + lsum1[1]) + (lsum1[2] + lsum1[3]);
  rsum1 += __shfl_xor(rsum1, 16);
  rsum1 += __shfl_xor(rsum1, 32);

  float* op = o_part + (size_t)kh * (8192ull * 384);
  int hd = bh - b * HEADS;
  size_t base0 = ((size_t)b * NSEQ + qrow0) * 384 + hd * 64;
  size_t base1 = ((size_t)b * NSEQ + qrow1) * 384 + hd * 64;
#pragma unroll
  for (int ds_ = 0; ds_ < 4; ++ds_) {
    *(f32x4*)(op + base0 + ds_ * 16 + lg * 4) = acc0[ds_];
    *(f32x4*)(op + base1 + ds_ * 16 + lg * 4) = acc1[ds_];
  }
  if (lg == 0) {
    l_part[(kh * 12 + bh) * NSEQ + qrow0] = rsum0;
    l_part[(kh * 12 + bh) * NSEQ + qrow1] = rsum1;
  }
#undef STAGE
}

// combine: masked q -> meanV; else (sum O_kh) / (sum l_kh); cast bf16
template <int KS>
__global__ void combine_kernel(const float* __restrict__ o_part, const float* __restrict__ l_part,
                               const float* __restrict__ madd, const float* __restrict__ meanv,
                               u16* __restrict__ out) {
  int i = blockIdx.x * blockDim.x + threadIdx.x;   // float4 index, 786432 total
  int elem = i * 4;
  int ng = elem / 384;
  int cc = elem - ng * 384;
  int h = cc >> 6, d = cc & 63;
  int b = ng >> 12, n = ng & 4095;
  int li = (b * HEADS + h) * NSEQ + n;

  float4 a = ((const float4*)o_part)[i];
  float lt = l_part[li];
#pragma unroll
  for (int kh = 1; kh < KS; ++kh) {
    float4 c = ((const float4*)(o_part + (size_t)kh * (8192ull * 384)))[i];
    a.x += c.x; a.y += c.y; a.z += c.z; a.w += c.w;
    lt += l_part[kh * 12 * NSEQ + li];
  }
  float inv = 1.0f / lt;
  float a0 = a.x * inv, a1 = a.y * inv, a2 = a.z * inv, a3 = a.w * inv;
  if (madd[ng] != 0.0f) {   // masked q row -> uniform attention = mean(V)
    const float* mv = meanv + (b * HEADS + h) * 64 + d;
    a0 = mv[0]; a1 = mv[1]; a2 = mv[2]; a3 = mv[3];
  }
  uint32_t w0, w1;
  asm("v_cvt_pk_bf16_f32 %0, %1, %2" : "=v"(w0) : "v"(a0), "v"(a1));
  asm("v_cvt_pk_bf16_f32 %0, %1, %2" : "=v"(w1) : "v"(a2), "v"(a3));
  uint2 st; st.x = w0; st.y = w1;
  *(uint2*)(out + elem) = st;
}

extern "C" void kernel_launch(void* const* d_in, const int* in_sizes, int n_in,
                              void* d_out, int out_size, void* d_ws, size_t ws_size,
                              hipStream_t stream) {
  const float* x = (const float*)d_in[0];
  const int* mask = (const int*)d_in[1];
  const float* w_qkv = (const float*)d_in[2];
  const float* w_proj = (const float*)d_in[3];
  const float* b_proj = (const float*)d_in[4];
  float* out = (float*)d_out;

  char* ws = (char*)d_ws;
  u16* x_bf = (u16*)(ws + 0);              //  8192x384
  u16* wqkv_bf = (u16*)(ws + 6291456);     //  1152x384
  u16* wproj_bf = (u16*)(ws + 7176192);    //   384x384
  u16* q_bf = (u16*)(ws + 7471104);        //  [b,h,n,d]
  u16* k_bf = (u16*)(ws + 13762560);       //  [b,h,nc_perm,d]
  u16* vt_bf = (u16*)(ws + 20054016);      //  [b,h,d,nc_perm]
  u16* attn_bf = (u16*)(ws + 26345472);    //  8192x384
  float* madd = (float*)(ws + 32636928);   //  [2][4096] f32, ends 32669696
  float* o_part = (float*)(ws + 32669696); //  2 x 8192x384 f32 = 25165824
  float* l_part = (float*)(ws + 57835520); //  2 x 12x4096 f32 = 393216; ends 58228736
  int* cpos = (int*)(ws + 58228736);       //  2x4096 int = 32768; ends 58261504
  float* acm = (float*)(ws + 58261504);    //  2x4096 f32 = 32768; ends 58294272
  int* nth = (int*)(ws + 58294272);        //  2 int (pad 16); ends 58294288
  float* meanv = (float*)(ws + 58294288);  //  768 f32 = 3072; ends 58297360

  // fused prep: 3 casts + mask addend
  const int NPREP = 3145728 / 8 + 442368 / 8 + 147456 / 8 + 2 * NSEQ;
  prep_kernel<<<(NPREP + 255) / 256, 256, 0, stream>>>(x, w_qkv, w_proj, mask,
                                                       x_bf, wqkv_bf, wproj_bf, madd);
  compact_kernel<<<2, 256, 0, stream>>>(mask, cpos, acm, nth);

  gemm_bt<0><<<dim3(64, 9), 256, 0, stream>>>(x_bf, wqkv_bf, 384, 1152,
                                              q_bf, k_bf, vt_bf, cpos, nullptr, nullptr);

  meanv_kernel<<<768, 64, 0, stream>>>(vt_bf, meanv);

  attn_kernel32<2><<<768, 256, 0, stream>>>(q_bf, k_bf, vt_bf, madd, acm, nth,
                                            o_part, l_part);
  combine_kernel<2><<<3072, 256, 0, stream>>>(o_part, l_part, madd, meanv, attn_bf);

  gemm_bt<1><<<dim3(64, 3), 256, 0, stream>>>(attn_bf, wproj_bf, 384, 384,
                                              nullptr, nullptr, nullptr, nullptr, b_proj, out);
}

// Round 17
// 93.088 us; speedup vs baseline: 1.3159x; 1.1731x over previous
//
#include <hip/hip_runtime.h>
#include <cfloat>
#include <cstdint>
#include <cstddef>

using u16 = unsigned short;
typedef __attribute__((ext_vector_type(8))) short short8;
typedef __attribute__((ext_vector_type(4))) float f32x4;

#define HEADS 6
#define NSEQ 4096
#define SCALEF 0.125f
#define LOG2E 1.4426950408889634f
#define SC2 (SCALEF * LOG2E)

#if __has_builtin(__builtin_amdgcn_exp2f)
#define EXP2(x) __builtin_amdgcn_exp2f(x)
#else
#define EXP2(x) exp2f(x)
#endif

__device__ __forceinline__ u16 f2bf_rn(float f) {
  unsigned int u = __builtin_bit_cast(unsigned int, f);
  u = (u + 0x7FFFu + ((u >> 16) & 1u)) >> 16;
  return (u16)u;
}

__device__ __forceinline__ void gload_lds16(const void* g, void* l) {
  __builtin_amdgcn_global_load_lds((const __attribute__((address_space(1))) void*)g,
                                   (__attribute__((address_space(3))) void*)l, 16, 0, 0);
}

// Swizzled b128 read from a [rows][64] u16 LDS tile (128B rows). (GEMM use)
__device__ __forceinline__ short8 frag_read(const u16* tile, int row, int blk) {
  int byt = row * 128 + ((blk * 16) ^ ((row & 7) << 4));
  return *(const short8*)((const char*)tile + byt);
}

__device__ __forceinline__ void cast8(const float* __restrict__ s, u16* __restrict__ d, int i) {
  const float4* sp = (const float4*)s;
  float4 a = sp[2 * i], b = sp[2 * i + 1];
  short8 r;
  r[0] = (short)f2bf_rn(a.x); r[1] = (short)f2bf_rn(a.y);
  r[2] = (short)f2bf_rn(a.z); r[3] = (short)f2bf_rn(a.w);
  r[4] = (short)f2bf_rn(b.x); r[5] = (short)f2bf_rn(b.y);
  r[6] = (short)f2bf_rn(b.z); r[7] = (short)f2bf_rn(b.w);
  ((short8*)d)[i] = r;
}

// fused prep: cast x / w_qkv / w_proj to bf16, mask -> float addend,
// + tail blocks (>= 1856) run the deterministic mask compaction.
__global__ void prep_kernel(const float* __restrict__ x, const float* __restrict__ wqkv,
                            const float* __restrict__ wproj, const int* __restrict__ mask,
                            u16* __restrict__ xb, u16* __restrict__ wqb, u16* __restrict__ wpb,
                            float* __restrict__ madd,
                            int* __restrict__ cpos, float* __restrict__ acm, int* __restrict__ nth) {
  __shared__ int cnt[256];
  __shared__ int offu[256];
  __shared__ int s_nc;
  const int NX = 3145728 / 8, NQ = 442368 / 8, NP = 147456 / 8;
  const int NPREP_BLK = 1856;   // (NX+NQ+NP+8192)/256
  if (blockIdx.x >= NPREP_BLK) {
    // compact for batch b (order-preserving: unmasked first, masked after)
    int b = blockIdx.x - NPREP_BLK;
    int t = threadIdx.x;
    const int* m = mask + b * NSEQ;
    int base = t * 16;
    int c = 0;
#pragma unroll
    for (int i = 0; i < 16; ++i) c += (m[base + i] != 0) ? 1 : 0;
    cnt[t] = c;
    __syncthreads();
    if (t == 0) {
      int s = 0;
      for (int i = 0; i < 256; ++i) { offu[i] = s; s += cnt[i]; }
      s_nc = s;
      int ncpad = (s + 127) & ~127;
      if (ncpad == 0) ncpad = 128;
      nth[b] = ncpad / 128;
    }
    __syncthreads();
    int nc = s_nc;
    int ou = offu[t];
    int om = base - ou;
    for (int i = 0; i < 16; ++i) {
      int n = base + i;
      int um = (m[n] != 0) ? 1 : 0;
      int pos = um ? ou : (nc + om);
      ou += um;
      om += 1 - um;
      cpos[b * NSEQ + n] = pos;
      acm[b * NSEQ + pos] = um ? 0.f : -FLT_MAX;
    }
    return;
  }
  int i = blockIdx.x * blockDim.x + threadIdx.x;
  if (i < NX) cast8(x, xb, i);
  else if (i < NX + NQ) cast8(wqkv, wqb, i - NX);
  else if (i < NX + NQ + NP) cast8(wproj, wpb, i - NX - NQ);
  else {
    int j = i - (NX + NQ + NP);
    if (j < 2 * NSEQ) madd[j] = mask[j] ? 0.f : -FLT_MAX;
  }
}

// meanV[bh*64+d] = mean over all 4096 k of V (permutation-invariant sum)
__global__ void meanv_kernel(const u16* __restrict__ vt, float* __restrict__ meanv) {
  int row = blockIdx.x;   // 768 = 12 bh * 64 d
  const u16* src = vt + (size_t)row * NSEQ + threadIdx.x * 8;
  float s = 0.f;
#pragma unroll
  for (int i = 0; i < 8; ++i) {
    short8 v = *(const short8*)(src + i * 512);
#pragma unroll
    for (int j = 0; j < 8; ++j) {
      unsigned int u = ((unsigned int)(unsigned short)v[j]) << 16;
      s += __builtin_bit_cast(float, u);
    }
  }
#pragma unroll
  for (int off = 1; off < 64; off <<= 1) s += __shfl_xor(s, off);
  if (threadIdx.x == 0) meanv[row] = s * (1.0f / NSEQ);
}

// C = A(MxK) * B(NxK)^T ; 128x128 tile, BK=64, 4 waves (2x2 of 64x64).
// EPI 0 scatters q/k/vt ALL in PERMUTED order via cpos.
template <int EPI>
__launch_bounds__(256)
__global__ void gemm_bt(const u16* __restrict__ A, const u16* __restrict__ B,
                        int Kdim, int Ndim,
                        u16* __restrict__ q_out, u16* __restrict__ k_out, u16* __restrict__ vt_out,
                        const int* __restrict__ cpos,
                        const float* __restrict__ bias, float* __restrict__ out) {
  __shared__ u16 lA[128 * 64];
  __shared__ u16 lB[128 * 64];
  int brow = blockIdx.x, bcol = blockIdx.y;
  int tid = threadIdx.x;
  int w = tid >> 6, lane = tid & 63;
  int wr = w >> 1, wc = w & 1;
  int r_in = lane >> 3;
  int jblk = (lane & 7) ^ r_in;
  int l15 = lane & 15, lg = lane >> 4;

  f32x4 acc[4][4];
#pragma unroll
  for (int i = 0; i < 4; i++)
#pragma unroll
    for (int j = 0; j < 4; j++) acc[i][j] = (f32x4){0.f, 0.f, 0.f, 0.f};

  const u16* Ab = A + (size_t)(brow * 128 + w * 32 + r_in) * Kdim + jblk * 8;
  const u16* Bb = B + (size_t)(bcol * 128 + w * 32 + r_in) * Kdim + jblk * 8;

  int ksteps = Kdim >> 6;
  for (int kt = 0; kt < ksteps; ++kt) {
    __syncthreads();
#pragma unroll
    for (int c = 0; c < 4; ++c) {
      gload_lds16(Ab + kt * 64 + (size_t)(c * 8) * Kdim, &lA[(w * 32 + c * 8) * 64]);
      gload_lds16(Bb + kt * 64 + (size_t)(c * 8) * Kdim, &lB[(w * 32 + c * 8) * 64]);
    }
    asm volatile("s_waitcnt vmcnt(0)" ::: "memory");
    __syncthreads();

    short8 af[4][2], bfr[4][2];
#pragma unroll
    for (int ms = 0; ms < 4; ++ms)
#pragma unroll
      for (int hf = 0; hf < 2; ++hf)
        af[ms][hf] = frag_read(lA, wr * 64 + ms * 16 + l15, hf * 4 + lg);
#pragma unroll
    for (int ns = 0; ns < 4; ++ns)
#pragma unroll
      for (int hf = 0; hf < 2; ++hf)
        bfr[ns][hf] = frag_read(lB, wc * 64 + ns * 16 + l15, hf * 4 + lg);
#pragma unroll
    for (int ms = 0; ms < 4; ++ms)
#pragma unroll
      for (int ns = 0; ns < 4; ++ns) {
        acc[ms][ns] = __builtin_amdgcn_mfma_f32_16x16x32_bf16(af[ms][0], bfr[ns][0], acc[ms][ns], 0, 0, 0);
        acc[ms][ns] = __builtin_amdgcn_mfma_f32_16x16x32_bf16(af[ms][1], bfr[ns][1], acc[ms][ns], 0, 0, 0);
      }
  }

#pragma unroll
  for (int ms = 0; ms < 4; ++ms)
#pragma unroll
    for (int ns = 0; ns < 4; ++ns)
#pragma unroll
      for (int r = 0; r < 4; ++r) {
        int row_g = brow * 128 + wr * 64 + ms * 16 + lg * 4 + r;
        int col_g = bcol * 128 + wc * 64 + ns * 16 + l15;
        float v = acc[ms][ns][r];
        if (EPI == 0) {
          int t = col_g / 384;
          int rem = col_g - t * 384;
          int h = rem >> 6, d = rem & 63;
          int b = row_g >> 12;
          u16 val = f2bf_rn(v);
          size_t bh = (size_t)(b * HEADS + h);
          int pp = cpos[row_g];              // permuted position (q AND k)
          if (t == 0)      q_out[(bh * NSEQ + pp) * 64 + d] = val;
          else if (t == 1) k_out[(bh * NSEQ + pp) * 64 + d] = val;
          else             vt_out[(bh * 64 + d) * NSEQ + pp] = val;
        } else {
          out[(size_t)row_g * Ndim + col_g] = v + bias[col_g];
        }
      }
}

// Flash attention over COMPACTED q AND k, QBLK=32/wave, KT=64, streaming
// softmax, KS-way k-split, dbuf LDS (R16-proven core). q-tiles qb >= nth[b]
// exit; kh k-ranges via integer-division splits of kt_total = 2*nth.
template <int KS>
__launch_bounds__(256, 3)
__global__ void attn_kernel32(const u16* __restrict__ qg, const u16* __restrict__ kg,
                              const u16* __restrict__ vtg,
                              const float* __restrict__ acm, const int* __restrict__ nth,
                              float* __restrict__ o_part, float* __restrict__ l_part) {
  __shared__ u16 lK[2][64 * 64];   // [buf][k_local][d], 128B rows, XOR key = row&7
  __shared__ u16 lV[2][64 * 64];   // [buf][d][k_local], 128B rows, XOR key = row&7

  // bijective XCD swizzle: 32*12*KS blocks, 48*KS per XCD; qb fastest
  int bid = blockIdx.x;
  int orig = (bid & 7) * (48 * KS) + (bid >> 3);
  int qb = orig & 31;
  int rr = orig >> 5;              // 0 .. 12*KS-1
  int bh = rr % 12, kh = rr / 12;

  int b = bh / HEADS;
  const int nt_b = nth[b];         // 128-row tiles of compacted length
  if (qb >= nt_b) return;          // q-tile beyond compacted q range (uniform)
  int kt_total = nt_b * 2;         // 64-k-tiles total
  int st = (kh * kt_total) / KS;
  int NTL = ((kh + 1) * kt_total) / KS - st;
  int kbase = st * 64;

  int tid = threadIdx.x;
  int w = tid >> 6, lane = tid & 63;
  int l15 = lane & 15, lg = lane >> 4;
  int r_in = lane >> 3, jblk = (lane & 7) ^ r_in;

  const u16* Q = qg + (size_t)bh * NSEQ * 64;
  const u16* K = kg + (size_t)bh * NSEQ * 64;
  const u16* VT = vtg + (size_t)bh * 64 * NSEQ;
  const float* acrow = acm + b * NSEQ;    // permuted-order mask addend (q and k)

  int q0 = qb * 128 + w * 32;             // permuted q position
  int qrow0 = q0 + l15, qrow1 = q0 + 16 + l15;
  short8 qfA[2], qfB[2];
#pragma unroll
  for (int hf = 0; hf < 2; ++hf) {
    qfA[hf] = *(const short8*)(Q + (size_t)qrow0 * 64 + hf * 32 + lg * 8);
    qfB[hf] = *(const short8*)(Q + (size_t)qrow1 * 64 + hf * 32 + lg * 8);
  }

  float qsel0 = (acrow[qrow0] == 0.0f) ? 1.0f : 0.0f;
  float qsel1 = (acrow[qrow1] == 0.0f) ? 1.0f : 0.0f;
  float scq0 = SC2 * qsel0, scq1 = SC2 * qsel1;

  // lane-constant swizzled read offsets (row = x*16 + l15 -> row&7 == l15&7)
  int swk = (l15 & 7) << 4;
  int offKA = l15 * 128 + ((lg * 16) ^ swk);
  int offKB = l15 * 128 + (((4 + lg) * 16) ^ swk);

  f32x4 acc0[4], acc1[4];
#pragma unroll
  for (int ds_ = 0; ds_ < 4; ++ds_) {
    acc0[ds_] = (f32x4){0.f, 0.f, 0.f, 0.f};
    acc1[ds_] = (f32x4){0.f, 0.f, 0.f, 0.f};
  }
  f32x4 lsum0 = (f32x4){0.f, 0.f, 0.f, 0.f};
  f32x4 lsum1 = (f32x4){0.f, 0.f, 0.f, 0.f};

#define STAGE(BUF, k0s)                                                                     \
  {                                                                                         \
    _Pragma("unroll")                                                                       \
    for (int c = 0; c < 2; ++c) {                                                           \
      int rowb = w * 16 + c * 8;                                                            \
      gload_lds16(K + (size_t)((k0s) + rowb + r_in) * 64 + jblk * 8, &lK[BUF][rowb * 64]);  \
      gload_lds16(VT + (size_t)(rowb + r_in) * NSEQ + (k0s) + jblk * 8, &lV[BUF][rowb * 64]);\
    }                                                                                       \
  }

  if (NTL > 0) {
    STAGE(0, kbase);
    asm volatile("s_waitcnt vmcnt(0)" ::: "memory");
    __syncthreads();

    int cur = 0;
    for (int t = 0; t < NTL; ++t) {
      if (t + 1 < NTL) STAGE(cur ^ 1, kbase + (t + 1) * 64);

      const char* kb = (const char*)lK[cur];
      const char* vb = (const char*)lV[cur];

      f32x4 p0[4], p1[4];
      __builtin_amdgcn_s_setprio(1);
#pragma unroll
      for (int cs = 0; cs < 4; ++cs) {
        short8 kf0 = *(const short8*)(kb + offKA + cs * 2048);
        short8 kf1 = *(const short8*)(kb + offKB + cs * 2048);
        f32x4 z0 = (f32x4){0.f, 0.f, 0.f, 0.f};
        f32x4 z1 = (f32x4){0.f, 0.f, 0.f, 0.f};
        z0 = __builtin_amdgcn_mfma_f32_16x16x32_bf16(kf0, qfA[0], z0, 0, 0, 0);
        z1 = __builtin_amdgcn_mfma_f32_16x16x32_bf16(kf0, qfB[0], z1, 0, 0, 0);
        p0[cs] = __builtin_amdgcn_mfma_f32_16x16x32_bf16(kf1, qfA[1], z0, 0, 0, 0);
        p1[cs] = __builtin_amdgcn_mfma_f32_16x16x32_bf16(kf1, qfB[1], z1, 0, 0, 0);
      }
      __builtin_amdgcn_s_setprio(0);

      int k0 = kbase + t * 64;
#pragma unroll
      for (int cs = 0; cs < 4; ++cs) {
        f32x4 mf = *(const f32x4*)(acrow + k0 + cs * 16 + lg * 4);
        f32x4 d0 = p0[cs] * scq0 + mf * qsel0;
        f32x4 d1 = p1[cs] * scq1 + mf * qsel1;
#pragma unroll
        for (int r = 0; r < 4; ++r) {
          p0[cs][r] = EXP2(d0[r]);
          p1[cs][r] = EXP2(d1[r]);
        }
      }
      lsum0 += (p0[0] + p0[1]) + (p0[2] + p0[3]);
      lsum1 += (p1[0] + p1[1]) + (p1[2] + p1[3]);

      short8 pfA[2], pfB[2];
      {
        uint32_t wd[4][2];
#pragma unroll
        for (int cs = 0; cs < 4; ++cs)
#pragma unroll
          for (int hh = 0; hh < 2; ++hh)
            asm("v_cvt_pk_bf16_f32 %0, %1, %2" : "=v"(wd[cs][hh]) : "v"(p0[cs][2 * hh]), "v"(p0[cs][2 * hh + 1]));
#pragma unroll
        for (int c = 0; c < 2; ++c) {
          union { uint32_t u[4]; short8 s8; } cv;
#pragma unroll
          for (int hh = 0; hh < 2; ++hh) {
            uint32_t A = wd[2 * c][hh], B = wd[2 * c + 1][hh];
            asm("v_permlane32_swap_b32 %0, %1" : "+v"(A), "+v"(B));
            asm("v_permlane16_swap_b32 %0, %1" : "+v"(A), "+v"(B));
            cv.u[hh] = A;
            cv.u[2 + hh] = B;
          }
          pfA[c] = cv.s8;
        }
      }
      {
        uint32_t wd[4][2];
#pragma unroll
        for (int cs = 0; cs < 4; ++cs)
#pragma unroll
          for (int hh = 0; hh < 2; ++hh)
            asm("v_cvt_pk_bf16_f32 %0, %1, %2" : "=v"(wd[cs][hh]) : "v"(p1[cs][2 * hh]), "v"(p1[cs][2 * hh + 1]));
#pragma unroll
        for (int c = 0; c < 2; ++c) {
          union { uint32_t u[4]; short8 s8; } cv;
#pragma unroll
          for (int hh = 0; hh < 2; ++hh) {
            uint32_t A = wd[2 * c][hh], B = wd[2 * c + 1][hh];
            asm("v_permlane32_swap_b32 %0, %1" : "+v"(A), "+v"(B));
            asm("v_permlane16_swap_b32 %0, %1" : "+v"(A), "+v"(B));
            cv.u[hh] = A;
            cv.u[2 + hh] = B;
          }
          pfB[c] = cv.s8;
        }
      }

      __builtin_amdgcn_s_setprio(1);
#pragma unroll
      for (int ds_ = 0; ds_ < 4; ++ds_) {
        short8 vf0 = *(const short8*)(vb + offKA + ds_ * 2048);
        short8 vf1 = *(const short8*)(vb + offKB + ds_ * 2048);
        acc0[ds_] = __builtin_amdgcn_mfma_f32_16x16x32_bf16(vf0, pfA[0], acc0[ds_], 0, 0, 0);
        acc0[ds_] = __builtin_amdgcn_mfma_f32_16x16x32_bf16(vf1, pfA[1], acc0[ds_], 0, 0, 0);
        acc1[ds_] = __builtin_amdgcn_mfma_f32_16x16x32_bf16(vf0, pfB[0], acc1[ds_], 0, 0, 0);
        acc1[ds_] = __builtin_amdgcn_mfma_f32_16x16x32_bf16(vf1, pfB[1], acc1[ds_], 0, 0, 0);
      }
      __builtin_amdgcn_s_setprio(0);

      __syncthreads();
      cur ^= 1;
    }
  }

  float rsum0 = (lsum0[0] + lsum0[1]) + (lsum0[2] + lsum0[3]);
  rsum0 += __shfl_xor(rsum0, 16);
  rsum0 += __shfl_xor(rsum0, 32);
  float rsum1 = (lsum1[0] + lsum1[1]) + (lsum1[2] + lsum1[3]);
  rsum1 += __shfl_xor(rsum1, 16);
  rsum1 += __shfl_xor(rsum1, 32);

  float* op = o_part + (size_t)kh * (8192ull * 384);
  int hd = bh - b * HEADS;
  size_t base0 = ((size_t)b * NSEQ + qrow0) * 384 + hd * 64;
  size_t base1 = ((size_t)b * NSEQ + qrow1) * 384 + hd * 64;
#pragma unroll
  for (int ds_ = 0; ds_ < 4; ++ds_) {
    *(f32x4*)(op + base0 + ds_ * 16 + lg * 4) = acc0[ds_];
    *(f32x4*)(op + base1 + ds_ * 16 + lg * 4) = acc1[ds_];
  }
  if (lg == 0) {
    l_part[(kh * 12 + bh) * NSEQ + qrow0] = rsum0;
    l_part[(kh * 12 + bh) * NSEQ + qrow1] = rsum1;
  }
#undef STAGE
}

// combine: masked q -> meanV; else gather partials at permuted pos, normalize.
template <int KS>
__global__ void combine_kernel(const float* __restrict__ o_part, const float* __restrict__ l_part,
                               const float* __restrict__ madd, const float* __restrict__ meanv,
                               const int* __restrict__ cpos, u16* __restrict__ out) {
  int i = blockIdx.x * blockDim.x + threadIdx.x;   // float4 index, 786432 total
  int elem = i * 4;
  int ng = elem / 384;      // b*4096 + n (original order)
  int cc = elem - ng * 384;
  int h = cc >> 6, d = cc & 63;
  int b = ng >> 12;

  float a0, a1, a2, a3;
  if (madd[ng] != 0.0f) {   // masked q -> uniform attention = mean(V)
    const float* mv = meanv + (b * HEADS + h) * 64 + d;
    a0 = mv[0]; a1 = mv[1]; a2 = mv[2]; a3 = mv[3];
  } else {
    int pos = cpos[ng];     // permuted q position
    size_t pbase = (size_t)(b * NSEQ + pos) * 384 + cc;
    int li = (b * HEADS + h) * NSEQ + pos;
    float4 a = *(const float4*)(o_part + pbase);
    float lt = l_part[li];
#pragma unroll
    for (int kh = 1; kh < KS; ++kh) {
      float4 c = *(const float4*)(o_part + (size_t)kh * (8192ull * 384) + pbase);
      a.x += c.x; a.y += c.y; a.z += c.z; a.w += c.w;
      lt += l_part[kh * 12 * NSEQ + li];
    }
    float inv = 1.0f / lt;
    a0 = a.x * inv; a1 = a.y * inv; a2 = a.z * inv; a3 = a.w * inv;
  }
  uint32_t w0, w1;
  asm("v_cvt_pk_bf16_f32 %0, %1, %2" : "=v"(w0) : "v"(a0), "v"(a1));
  asm("v_cvt_pk_bf16_f32 %0, %1, %2" : "=v"(w1) : "v"(a2), "v"(a3));
  uint2 st; st.x = w0; st.y = w1;
  *(uint2*)(out + elem) = st;
}

extern "C" void kernel_launch(void* const* d_in, const int* in_sizes, int n_in,
                              void* d_out, int out_size, void* d_ws, size_t ws_size,
                              hipStream_t stream) {
  const float* x = (const float*)d_in[0];
  const int* mask = (const int*)d_in[1];
  const float* w_qkv = (const float*)d_in[2];
  const float* w_proj = (const float*)d_in[3];
  const float* b_proj = (const float*)d_in[4];
  float* out = (float*)d_out;

  char* ws = (char*)d_ws;
  u16* x_bf = (u16*)(ws + 0);              //  ends  6291456
  u16* wqkv_bf = (u16*)(ws + 6291456);     //  ends  7176192
  u16* wproj_bf = (u16*)(ws + 7176192);    //  ends  7471104
  u16* q_bf = (u16*)(ws + 7471104);        //  ends 13762560  [b,h,nperm,d]
  u16* k_bf = (u16*)(ws + 13762560);       //  ends 20054016  [b,h,nperm,d]
  u16* vt_bf = (u16*)(ws + 20054016);      //  ends 26345472  [b,h,d,nperm]
  u16* attn_bf = (u16*)(ws + 26345472);    //  ends 32636928
  float* madd = (float*)(ws + 32636928);   //  ends 32669696
  int* cpos = (int*)(ws + 32669696);       //  ends 32702464
  float* acm = (float*)(ws + 32702464);    //  ends 32735232
  int* nth = (int*)(ws + 32735232);        //  ends 32735296 (padded)
  float* meanv = (float*)(ws + 32735296);  //  ends 32738368; pad to 32738432
  float* o_part = (float*)(ws + 32738432); //  KS x 12582912
  // l_part placed after o_part per KS below

  const int NPREP_GRID = 1856 + 2;   // prep blocks + 2 compact blocks
  prep_kernel<<<NPREP_GRID, 256, 0, stream>>>(x, w_qkv, w_proj, mask,
                                              x_bf, wqkv_bf, wproj_bf, madd,
                                              cpos, acm, nth);

  gemm_bt<0><<<dim3(64, 9), 256, 0, stream>>>(x_bf, wqkv_bf, 384, 1152,
                                              q_bf, k_bf, vt_bf, cpos, nullptr, nullptr);

  meanv_kernel<<<768, 64, 0, stream>>>(vt_bf, meanv);

  if (ws_size >= 32738432ull + 4ull * 12582912 + 4ull * 196608) {       // 83856512
    float* l_part = (float*)(ws + 32738432 + 4ull * 12582912);          // 83070080
    attn_kernel32<4><<<1536, 256, 0, stream>>>(q_bf, k_bf, vt_bf, acm, nth, o_part, l_part);
    combine_kernel<4><<<3072, 256, 0, stream>>>(o_part, l_part, madd, meanv, cpos, attn_bf);
  } else {
    float* l_part = (float*)(ws + 32738432 + 2ull * 12582912);          // 57904256
    attn_kernel32<2><<<768, 256, 0, stream>>>(q_bf, k_bf, vt_bf, acm, nth, o_part, l_part);
    combine_kernel<2><<<3072, 256, 0, stream>>>(o_part, l_part, madd, meanv, cpos, attn_bf);
  }

  gemm_bt<1><<<dim3(64, 3), 256, 0, stream>>>(attn_bf, wproj_bf, 384, 384,
                                              nullptr, nullptr, nullptr, nullptr, b_proj, out);
}